// Round 1
// baseline (4408.329 us; speedup 1.0000x reference)
//
#include <hip/hip_runtime.h>
#include <math.h>

// Problem constants
#define T_LEN 2048
#define DM    2048
#define NH    16
#define HD    128     // DK == DV == 128
#define CDIM  6144    // NH*2*DK + NH*DV
#define GH    768     // GEN_HIDDEN
#define NOUT  24576   // CDIM * W

__device__ __forceinline__ float silu_f(float v) { return v / (1.f + __expf(-v)); }

// ---------------------------------------------------------------------------
// Generic fp32 tiled GEMM: C[M,N] = A[M,K] @ B[K,N], row-major.
// 256 threads, thread computes TM x TN in split halves (conflict-friendly).
// EPI: 0 = none, 1 = silu
// ---------------------------------------------------------------------------
template<int BM, int BN, int BK, int TM, int TN, int EPI>
__global__ __launch_bounds__(256)
void sgemm(const float* __restrict__ A, const float* __restrict__ B,
           float* __restrict__ C, int M, int N, int K)
{
    constexpr int HTM = TM / 2, HTN = TN / 2;
    __shared__ float As[BK][BM + 4];
    __shared__ float Bs[BK][BN + 4];
    const int tid = threadIdx.x;
    const int tx = tid & 15, ty = tid >> 4;
    const int bm0 = blockIdx.y * BM, bn0 = blockIdx.x * BN;

    float acc[TM][TN];
#pragma unroll
    for (int i = 0; i < TM; i++)
#pragma unroll
        for (int j = 0; j < TN; j++) acc[i][j] = 0.f;

    for (int k0 = 0; k0 < K; k0 += BK) {
#pragma unroll
        for (int l = tid; l < BM * BK / 4; l += 256) {
            int row = l / (BK / 4);
            int kq  = (l % (BK / 4)) * 4;
            float4 v = *(const float4*)&A[(size_t)(bm0 + row) * K + k0 + kq];
            As[kq + 0][row] = v.x; As[kq + 1][row] = v.y;
            As[kq + 2][row] = v.z; As[kq + 3][row] = v.w;
        }
#pragma unroll
        for (int l = tid; l < BK * BN / 4; l += 256) {
            int kk = l / (BN / 4);
            int nq = (l % (BN / 4)) * 4;
            *(float4*)&Bs[kk][nq] = *(const float4*)&B[(size_t)(k0 + kk) * N + bn0 + nq];
        }
        __syncthreads();
#pragma unroll
        for (int kk = 0; kk < BK; kk++) {
            float a[TM], b[TN];
#pragma unroll
            for (int i = 0; i < HTM; i++) {
                a[i]       = As[kk][ty * HTM + i];
                a[i + HTM] = As[kk][BM / 2 + ty * HTM + i];
            }
#pragma unroll
            for (int j = 0; j < HTN; j++) {
                b[j]       = Bs[kk][tx * HTN + j];
                b[j + HTN] = Bs[kk][BN / 2 + tx * HTN + j];
            }
#pragma unroll
            for (int i = 0; i < TM; i++)
#pragma unroll
                for (int j = 0; j < TN; j++) acc[i][j] += a[i] * b[j];
        }
        __syncthreads();
    }

#pragma unroll
    for (int i = 0; i < TM; i++) {
        int r = bm0 + ((i < HTM) ? ty * HTM + i : BM / 2 + ty * HTM + (i - HTM));
#pragma unroll
        for (int j = 0; j < TN; j++) {
            int c = bn0 + ((j < HTN) ? tx * HTN + j : BN / 2 + tx * HTN + (j - HTN));
            float v = acc[i][j];
            if (EPI == 1) v = silu_f(v);
            C[(size_t)r * N + c] = v;
        }
    }
}

// ---------------------------------------------------------------------------
// Fused generator-GEMM2 + dynamic causal conv + silu.
//   kern[t, d, w] = h1[t,:] @ gen_w2[:, d*4+w] + gen_b2[d*4+w]
//   out[t, d]     = silu( sum_w kern[t,d,w] * u[t-3+w, d] )
// A = h1 [2048 x 768], B = gen_w2 [768 x 24576]. 128x128 B-column tile = 32 d.
// Never materializes the 201 MB kern tensor.
// ---------------------------------------------------------------------------
__global__ __launch_bounds__(256)
void convgen(const float* __restrict__ A, const float* __restrict__ B,
             const float* __restrict__ b2, const float* __restrict__ u,
             float* __restrict__ out)
{
    constexpr int BM = 128, BN = 128, BK = 16;
    const int K = GH, N = NOUT;
    __shared__ float As[BK][BM + 4];
    __shared__ float Bs[BK][BN + 4];
    const int tid = threadIdx.x;
    const int tx = tid & 15, ty = tid >> 4;
    const int bm0 = blockIdx.y * BM, bn0 = blockIdx.x * BN;

    float acc[8][8];
#pragma unroll
    for (int i = 0; i < 8; i++)
#pragma unroll
        for (int j = 0; j < 8; j++) acc[i][j] = 0.f;

    for (int k0 = 0; k0 < K; k0 += BK) {
#pragma unroll
        for (int l = tid; l < BM * BK / 4; l += 256) {
            int row = l / (BK / 4);
            int kq  = (l % (BK / 4)) * 4;
            float4 v = *(const float4*)&A[(size_t)(bm0 + row) * K + k0 + kq];
            As[kq + 0][row] = v.x; As[kq + 1][row] = v.y;
            As[kq + 2][row] = v.z; As[kq + 3][row] = v.w;
        }
#pragma unroll
        for (int l = tid; l < BK * BN / 4; l += 256) {
            int kk = l / (BN / 4);
            int nq = (l % (BN / 4)) * 4;
            *(float4*)&Bs[kk][nq] = *(const float4*)&B[(size_t)(k0 + kk) * N + bn0 + nq];
        }
        __syncthreads();
#pragma unroll
        for (int kk = 0; kk < BK; kk++) {
            float a[8], b[8];
#pragma unroll
            for (int i = 0; i < 4; i++) {
                a[i]     = As[kk][ty * 4 + i];
                a[i + 4] = As[kk][64 + ty * 4 + i];
            }
#pragma unroll
            for (int j = 0; j < 4; j++) {
                b[j]     = Bs[kk][tx * 4 + j];
                b[j + 4] = Bs[kk][64 + tx * 4 + j];
            }
#pragma unroll
            for (int i = 0; i < 8; i++)
#pragma unroll
                for (int j = 0; j < 8; j++) acc[i][j] += a[i] * b[j];
        }
        __syncthreads();
    }

    // Conv epilogue: thread's 2 column-groups of 4 == d = bn0/4 + tx, bn0/4+16+tx
#pragma unroll
    for (int i = 0; i < 8; i++) {
        int r = bm0 + ((i < 4) ? ty * 4 + i : 64 + ty * 4 + (i - 4));
#pragma unroll
        for (int g = 0; g < 2; g++) {
            int d = (bn0 >> 2) + g * 16 + tx;
            float val = 0.f;
#pragma unroll
            for (int w = 0; w < 4; w++) {
                float kern = acc[i][g * 4 + w] + b2[d * 4 + w];
                int tr = r - 3 + w;
                if (tr >= 0) val += kern * u[(size_t)tr * CDIM + d];
            }
            out[(size_t)r * CDIM + d] = silu_f(val);
        }
    }
}

// ---------------------------------------------------------------------------
// ba = x @ W_ba; beta = sigmoid(b); decay = exp(-softplus(a)) == sigmoid(-a)
// ---------------------------------------------------------------------------
__global__ __launch_bounds__(256)
void ba_kernel(const float* __restrict__ x, const float* __restrict__ Wba,
               float* __restrict__ beta, float* __restrict__ dec)
{
    int gid = blockIdx.x * 256 + threadIdx.x;   // [0, T*32)
    int t = gid >> 5, c = gid & 31;
    const float* xr = x + (size_t)t * DM;
    float s = 0.f;
#pragma unroll 4
    for (int k = 0; k < DM; k++) s = fmaf(xr[k], Wba[k * 32 + c], s);
    float val = 1.f / (1.f + expf((c < 16) ? -s : s));
    if (c < 16) beta[t * 16 + c] = val;
    else        dec [t * 16 + (c - 16)] = val;
}

// ---------------------------------------------------------------------------
// In-place l2norm of q and k head-rows of the conv output (q also * DK^-0.5).
// One wave per row of 128.
// ---------------------------------------------------------------------------
__global__ __launch_bounds__(256)
void norm_qk(float* __restrict__ cv)
{
    int gw = (blockIdx.x * 256 + threadIdx.x) >> 6;   // [0, T*32)
    int lane = threadIdx.x & 63;
    int t = gw >> 5, rest = gw & 31, sec = rest >> 4, h = rest & 15;
    float* p = cv + (size_t)t * CDIM + sec * (NH * HD) + h * HD;
    float x0 = p[lane], x1 = p[lane + 64];
    float ss = x0 * x0 + x1 * x1;
#pragma unroll
    for (int m = 32; m >= 1; m >>= 1) ss += __shfl_xor(ss, m);
    float sc = rsqrtf(ss + 1e-6f);
    if (sec == 0) sc *= 0.08838834764831845f;   // DK^-0.5
    p[lane] = x0 * sc; p[lane + 64] = x1 * sc;
}

// ---------------------------------------------------------------------------
// Gated delta rule scan. State column independence: S[:,v] is a private
// 128-vector recurrence. 16 lanes per column, 8 state rows per lane (VGPRs).
// Reduction via 4 DPP row_ror adds (16-lane rows align with column groups).
// ---------------------------------------------------------------------------
template<int CTRL>
__device__ __forceinline__ float dpp_add(float x) {
    int y = __builtin_amdgcn_mov_dpp(__float_as_int(x), CTRL, 0xF, 0xF, true);
    return x + __int_as_float(y);
}
__device__ __forceinline__ float reduce16(float x) {
    x = dpp_add<0x128>(x);   // row_ror:8
    x = dpp_add<0x124>(x);   // row_ror:4
    x = dpp_add<0x122>(x);   // row_ror:2
    x = dpp_add<0x121>(x);   // row_ror:1
    return x;
}

__global__ __launch_bounds__(256)
void scan_kernel(const float* __restrict__ cv, const float* __restrict__ beta,
                 const float* __restrict__ dec, float* __restrict__ o)
{
    const int wid  = (blockIdx.x * 256 + threadIdx.x) >> 6;  // [0,512)
    const int lane = threadIdx.x & 63;
    const int h    = wid >> 5;                                // 32 waves/head
    const int col  = ((wid & 31) << 2) | (lane >> 4);         // [0,128)
    const int rb   = (lane & 15) << 3;                        // 8 rows per lane
    const float* qp = cv + h * HD + rb;
    const float* kp = cv + NH * HD + h * HD + rb;
    const float* vp = cv + 2 * NH * HD + h * HD + col;

    float s[8];
#pragma unroll
    for (int i = 0; i < 8; i++) s[i] = 0.f;

    // prefetch t = 0
    float4 ka = *(const float4*)(kp),     kb = *(const float4*)(kp + 4);
    float4 qa = *(const float4*)(qp),     qb = *(const float4*)(qp + 4);
    float  vv = *vp;
    float  dd = dec[h], bb = beta[h];

    for (int t = 0; t < T_LEN; t++) {
        // prefetch t+1 (clamped; dead on last iter)
        int tn = (t + 1 < T_LEN) ? t + 1 : t;
        size_t off2 = (size_t)tn * CDIM;
        float4 ka2 = *(const float4*)(kp + off2), kb2 = *(const float4*)(kp + off2 + 4);
        float4 qa2 = *(const float4*)(qp + off2), qb2 = *(const float4*)(qp + off2 + 4);
        float  vv2 = vp[off2];
        float  dd2 = dec[tn * NH + h], bb2 = beta[tn * NH + h];

        // pred = decay * (k . s)  — decay folded after the reduce to keep it
        // off the serial chain; decayed state computed during the reduce.
        float part = ((ka.x * s[0] + ka.y * s[1]) + (ka.z * s[2] + ka.w * s[3]))
                   + ((kb.x * s[4] + kb.y * s[5]) + (kb.z * s[6] + kb.w * s[7]));
        float pred = reduce16(part) * dd;
        float uu = bb * (vv - pred);
        s[0] = fmaf(ka.x, uu, dd * s[0]);
        s[1] = fmaf(ka.y, uu, dd * s[1]);
        s[2] = fmaf(ka.z, uu, dd * s[2]);
        s[3] = fmaf(ka.w, uu, dd * s[3]);
        s[4] = fmaf(kb.x, uu, dd * s[4]);
        s[5] = fmaf(kb.y, uu, dd * s[5]);
        s[6] = fmaf(kb.z, uu, dd * s[6]);
        s[7] = fmaf(kb.w, uu, dd * s[7]);
        float op = ((qa.x * s[0] + qa.y * s[1]) + (qa.z * s[2] + qa.w * s[3]))
                 + ((qb.x * s[4] + qb.y * s[5]) + (qb.z * s[6] + qb.w * s[7]));
        op = reduce16(op);
        if ((lane & 15) == 0) o[(size_t)t * DM + h * HD + col] = op;

        ka = ka2; kb = kb2; qa = qa2; qb = qb2; vv = vv2; dd = dd2; bb = bb2;
    }
}

// ---------------------------------------------------------------------------
// Workspace layout (floats):
//   [0)            u = x@W_qkv   2048*6144   (reused for o = [2048,2048] later)
//   [12582912)     cv (conv out) 2048*6144
//   [25165824)     h1            2048*768
//   [26738688)     beta          2048*16
//   [26771456)     decay         2048*16
// total ~107.2 MB
// ---------------------------------------------------------------------------
extern "C" void kernel_launch(void* const* d_in, const int* in_sizes, int n_in,
                              void* d_out, int out_size, void* d_ws, size_t ws_size,
                              hipStream_t stream)
{
    const float* x      = (const float*)d_in[0];
    const float* W_qkv  = (const float*)d_in[1];
    const float* W_ba   = (const float*)d_in[2];
    const float* gen_w1 = (const float*)d_in[3];
    const float* gen_w2 = (const float*)d_in[4];
    const float* gen_b2 = (const float*)d_in[5];
    const float* W_o    = (const float*)d_in[6];
    float* y  = (float*)d_out;
    float* ws = (float*)d_ws;

    float* u    = ws;
    float* cv   = ws + 12582912;
    float* h1   = ws + 25165824;
    float* beta = ws + 26738688;
    float* decv = ws + 26771456;
    float* o    = ws;   // reuse u buffer (dead after convgen)

    dim3 blk(256);
    // 1. u = x @ W_qkv                      [2048,2048]x[2048,6144]
    sgemm<128,128,16,8,8,0><<<dim3(48,16), blk, 0, stream>>>(x, W_qkv, u, T_LEN, CDIM, DM);
    // 2. beta/decay from x @ W_ba
    ba_kernel<<<dim3(256), blk, 0, stream>>>(x, W_ba, beta, decv);
    // 3. h1 = silu(u @ gen_w1)              [2048,6144]x[6144,768]
    sgemm<64,64,16,4,4,1><<<dim3(12,32), blk, 0, stream>>>(u, gen_w1, h1, T_LEN, GH, CDIM);
    // 4. cv = silu(conv(u, h1@gen_w2+b2))   fused, no kern materialization
    convgen<<<dim3(192,16), blk, 0, stream>>>(h1, gen_w2, gen_b2, u, cv);
    // 5. l2norm q,k in place
    norm_qk<<<dim3(16384), blk, 0, stream>>>(cv);
    // 6. gated delta rule scan -> o
    scan_kernel<<<dim3(128), blk, 0, stream>>>(cv, beta, decv, o);
    // 7. y = o @ W_o                        [2048,2048]x[2048,2048]
    sgemm<128,128,16,8,8,0><<<dim3(16,16), blk, 0, stream>>>(o, W_o, y, T_LEN, DM, DM);
}

// Round 2
// 1385.393 us; speedup vs baseline: 3.1820x; 3.1820x over previous
//
#include <hip/hip_runtime.h>
#include <math.h>

#define T_LEN 2048
#define DM    2048
#define NH    16
#define HD    128
#define CDIM  6144
#define GH    768
#define NOUT  24576
#define CH    32

typedef unsigned short bf16_t;
typedef unsigned int   uint32;
typedef __attribute__((ext_vector_type(8))) short short8;
typedef __attribute__((ext_vector_type(4))) float f32x4;

__device__ __forceinline__ float silu_f(float v) { return v / (1.f + __expf(-v)); }

__device__ __forceinline__ bf16_t f2bf(float f) {
    uint32 u = __float_as_uint(f);
    u = (u + 0x7fff + ((u >> 16) & 1)) >> 16;   // RNE
    return (bf16_t)u;
}
__device__ __forceinline__ float bf2f(bf16_t b) {
    return __uint_as_float(((uint32)b) << 16);
}

// async global->LDS, 16B per lane; lds ptr must be wave-uniform (dest = base + lane*16)
#define GLL(gptr, lptr) \
  __builtin_amdgcn_global_load_lds((const __attribute__((address_space(1))) void*)(gptr), \
                                   (__attribute__((address_space(3))) void*)(lptr), 16, 0, 0)

// ---------------------------------------------------------------------------
// Transpose + cast: W [K][N] fp32 -> Wt [N][K] bf16
// ---------------------------------------------------------------------------
__global__ __launch_bounds__(256)
void tcast(const float* __restrict__ W, bf16_t* __restrict__ Wt, int K, int N)
{
    __shared__ float tile[32][33];
    const int n0 = blockIdx.x * 32, k0 = blockIdx.y * 32;
    const int c = threadIdx.x & 31, r = threadIdx.x >> 5;   // r in 0..7
#pragma unroll
    for (int i = 0; i < 4; i++)
        tile[r + i * 8][c] = W[(size_t)(k0 + r + i * 8) * N + n0 + c];
    __syncthreads();
#pragma unroll
    for (int i = 0; i < 4; i++)
        Wt[(size_t)(n0 + r + i * 8) * K + k0 + c] = f2bf(tile[c][r + i * 8]);
}

// elementwise fp32 -> bf16 (4 per thread)
__global__ __launch_bounds__(256)
void castk(const float* __restrict__ in, bf16_t* __restrict__ out, int n4)
{
    int i = blockIdx.x * 256 + threadIdx.x;
    if (i >= n4) return;
    float4 v = ((const float4*)in)[i];
    uint2 p;
    p.x = (uint32)f2bf(v.x) | ((uint32)f2bf(v.y) << 16);
    p.y = (uint32)f2bf(v.z) | ((uint32)f2bf(v.w) << 16);
    ((uint2*)out)[i] = p;
}

// ---------------------------------------------------------------------------
// bf16 MFMA GEMM, m97 structure: C[M,N] = A[M,K] @ Bt[N,K]^T
// 128x128 tile, BK=32, global_load_lds staging, oct-major LDS layout.
// EPI: 0 = fp32 store, 1 = bf16 store, 2 = silu + bf16 store
// ---------------------------------------------------------------------------
template<int EPI>
__global__ __launch_bounds__(256)
void mgemm(const bf16_t* __restrict__ A, const bf16_t* __restrict__ Bt,
           float* __restrict__ C, bf16_t* __restrict__ C16,
           int M, int N, int K)
{
    __shared__ bf16_t As[4096];   // [oct 4][row 128][8]
    __shared__ bf16_t Bs[4096];
    const int tid = threadIdx.x;
    const int lane = tid & 63, w = tid >> 6;
    const int quad = lane >> 4, tl = lane & 15;
    const int bm0 = blockIdx.y * 128, bn0 = blockIdx.x * 128;
    const int wm = (w >> 1) * 64, wn = (w & 1) * 64;

    const bf16_t* a0 = A  + (size_t)(bm0 + (tid & 127)) * K + ((tid >> 7) << 3);
    const bf16_t* b0 = Bt + (size_t)(bn0 + (tid & 127)) * K + ((tid >> 7) << 3);
    bf16_t* asd0 = &As[w * 512];
    bf16_t* asd1 = &As[2048 + w * 512];
    bf16_t* bsd0 = &Bs[w * 512];
    bf16_t* bsd1 = &Bs[2048 + w * 512];

    f32x4 acc[4][4];
#pragma unroll
    for (int i = 0; i < 4; i++)
#pragma unroll
        for (int j = 0; j < 4; j++) { acc[i][j][0] = 0.f; acc[i][j][1] = 0.f; acc[i][j][2] = 0.f; acc[i][j][3] = 0.f; }

    for (int k0 = 0; k0 < K; k0 += 32) {
        __syncthreads();
        GLL(a0 + k0,      asd0);
        GLL(a0 + k0 + 16, asd1);
        GLL(b0 + k0,      bsd0);
        GLL(b0 + k0 + 16, bsd1);
        __syncthreads();
        short8 af[4], bfr[4];
#pragma unroll
        for (int mt = 0; mt < 4; mt++)
            af[mt] = *(const short8*)&As[(quad * 128 + wm + mt * 16 + tl) * 8];
#pragma unroll
        for (int nt = 0; nt < 4; nt++)
            bfr[nt] = *(const short8*)&Bs[(quad * 128 + wn + nt * 16 + tl) * 8];
#pragma unroll
        for (int mt = 0; mt < 4; mt++)
#pragma unroll
            for (int nt = 0; nt < 4; nt++)
                acc[mt][nt] = __builtin_amdgcn_mfma_f32_16x16x32_bf16(af[mt], bfr[nt], acc[mt][nt], 0, 0, 0);
    }

#pragma unroll
    for (int mt = 0; mt < 4; mt++) {
        int rbase = bm0 + wm + mt * 16 + quad * 4;
#pragma unroll
        for (int nt = 0; nt < 4; nt++) {
            int cg = bn0 + wn + nt * 16 + tl;
#pragma unroll
            for (int r = 0; r < 4; r++) {
                float v = acc[mt][nt][r];
                size_t idx = (size_t)(rbase + r) * N + cg;
                if (EPI == 0)      C[idx]   = v;
                else if (EPI == 1) C16[idx] = f2bf(v);
                else               C16[idx] = f2bf(silu_f(v));
            }
        }
    }
}

// ---------------------------------------------------------------------------
// convgen: kern = h1 @ gen_w2 + b2 (MFMA), fused causal W=4 conv + silu.
// A = h1_bf16 [2048][768], Bt = gen_w2^T [24576][768], u16 = conv input (bf16),
// cv = fp32 output [2048][6144]. Quad-shuffle reduces the 4 w-taps per d.
// ---------------------------------------------------------------------------
__global__ __launch_bounds__(256)
void convgen(const bf16_t* __restrict__ A, const bf16_t* __restrict__ Bt,
             const float* __restrict__ b2, const bf16_t* __restrict__ u16c,
             float* __restrict__ cvout)
{
    const int K = GH;
    __shared__ bf16_t As[4096];
    __shared__ bf16_t Bs[4096];
    const int tid = threadIdx.x;
    const int lane = tid & 63, w = tid >> 6;
    const int quad = lane >> 4, tl = lane & 15;
    const int bm0 = blockIdx.y * 128, bn0 = blockIdx.x * 128;
    const int wm = (w >> 1) * 64, wn = (w & 1) * 64;

    const bf16_t* a0 = A  + (size_t)(bm0 + (tid & 127)) * K + ((tid >> 7) << 3);
    const bf16_t* b0 = Bt + (size_t)(bn0 + (tid & 127)) * K + ((tid >> 7) << 3);
    bf16_t* asd0 = &As[w * 512];
    bf16_t* asd1 = &As[2048 + w * 512];
    bf16_t* bsd0 = &Bs[w * 512];
    bf16_t* bsd1 = &Bs[2048 + w * 512];

    f32x4 acc[4][4];
#pragma unroll
    for (int i = 0; i < 4; i++)
#pragma unroll
        for (int j = 0; j < 4; j++) { acc[i][j][0] = 0.f; acc[i][j][1] = 0.f; acc[i][j][2] = 0.f; acc[i][j][3] = 0.f; }

    for (int k0 = 0; k0 < K; k0 += 32) {
        __syncthreads();
        GLL(a0 + k0,      asd0);
        GLL(a0 + k0 + 16, asd1);
        GLL(b0 + k0,      bsd0);
        GLL(b0 + k0 + 16, bsd1);
        __syncthreads();
        short8 af[4], bfr[4];
#pragma unroll
        for (int mt = 0; mt < 4; mt++)
            af[mt] = *(const short8*)&As[(quad * 128 + wm + mt * 16 + tl) * 8];
#pragma unroll
        for (int nt = 0; nt < 4; nt++)
            bfr[nt] = *(const short8*)&Bs[(quad * 128 + wn + nt * 16 + tl) * 8];
#pragma unroll
        for (int mt = 0; mt < 4; mt++)
#pragma unroll
            for (int nt = 0; nt < 4; nt++)
                acc[mt][nt] = __builtin_amdgcn_mfma_f32_16x16x32_bf16(af[mt], bfr[nt], acc[mt][nt], 0, 0, 0);
    }

#pragma unroll
    for (int nt = 0; nt < 4; nt++) {
        int n = bn0 + wn + nt * 16 + tl;
        int d = n >> 2, wi = n & 3;
        float b2v = b2[n];
#pragma unroll
        for (int mt = 0; mt < 4; mt++) {
            int rbase = bm0 + wm + mt * 16 + quad * 4;
#pragma unroll
            for (int r = 0; r < 4; r++) {
                int t = rbase + r;
                float kern = acc[mt][nt][r] + b2v;
                int tr = t - 3 + wi;
                float uval = (tr >= 0) ? bf2f(u16c[(size_t)tr * CDIM + d]) : 0.f;
                float p = kern * uval;
                p += __shfl_xor(p, 1);
                p += __shfl_xor(p, 2);
                if ((tl & 3) == 0) cvout[(size_t)t * CDIM + d] = silu_f(p);
            }
        }
    }
}

// ---------------------------------------------------------------------------
// ba: one wave per t. beta=sigmoid(b), decay=sigmoid(-a). Transposed outputs
// [H][T] so the scan can stage them with contiguous 16B loads.
// ---------------------------------------------------------------------------
__global__ __launch_bounds__(256)
void ba_kernel(const float* __restrict__ x, const float* __restrict__ Wba,
               float* __restrict__ betaT, float* __restrict__ decT)
{
    const int t = (blockIdx.x * 256 + threadIdx.x) >> 6;
    const int lane = threadIdx.x & 63;
    const int c = lane & 31, kh = lane >> 5;
    const float* xr = x + (size_t)t * DM + kh * 1024;
    const float* wb = Wba + (size_t)kh * 1024 * 32 + c;
    float s = 0.f;
#pragma unroll 8
    for (int k = 0; k < 1024; k++) s = fmaf(xr[k], wb[k * 32], s);
    s += __shfl_xor(s, 32);
    if (kh == 0) {
        float val = 1.f / (1.f + __expf((c < 16) ? -s : s));
        if (c < 16) betaT[(size_t)c * T_LEN + t] = val;
        else        decT[(size_t)(c - 16) * T_LEN + t] = val;
    }
}

// ---------------------------------------------------------------------------
// In-place l2norm of q,k rows (q also * DK^-0.5). One wave per 128-row.
// ---------------------------------------------------------------------------
__global__ __launch_bounds__(256)
void norm_qk(float* __restrict__ cv)
{
    int gw = (blockIdx.x * 256 + threadIdx.x) >> 6;
    int lane = threadIdx.x & 63;
    int t = gw >> 5, rest = gw & 31, sec = rest >> 4, h = rest & 15;
    float* p = cv + (size_t)t * CDIM + sec * (NH * HD) + h * HD;
    float x0 = p[lane], x1 = p[lane + 64];
    float ss = x0 * x0 + x1 * x1;
#pragma unroll
    for (int m = 32; m >= 1; m >>= 1) ss += __shfl_xor(ss, m);
    float sc = rsqrtf(ss + 1e-6f);
    if (sec == 0) sc *= 0.08838834764831845f;
    p[lane] = x0 * sc; p[lane + 64] = x1 * sc;
}

// ---------------------------------------------------------------------------
// Gated delta-rule scan, LDS double-buffered chunks of CH=32 timesteps.
// Block = 1 (head, 16-col group); 16 lanes/column, 8 state rows/lane.
// global_load_lds stages chunk c+1 while chunk c computes from LDS.
// ---------------------------------------------------------------------------
template<int CTRL>
__device__ __forceinline__ float dpp_add(float x) {
    int y = __builtin_amdgcn_mov_dpp(__float_as_int(x), CTRL, 0xF, 0xF, true);
    return x + __int_as_float(y);
}
__device__ __forceinline__ float reduce16(float x) {
    x = dpp_add<0x128>(x);
    x = dpp_add<0x124>(x);
    x = dpp_add<0x122>(x);
    x = dpp_add<0x121>(x);
    return x;
}

__global__ __launch_bounds__(256)
void scan_kernel(const float* __restrict__ cv, const float* __restrict__ betaT,
                 const float* __restrict__ decT, bf16_t* __restrict__ o16)
{
    __shared__ float q_s[2][CH][HD];
    __shared__ float k_s[2][CH][HD];
    __shared__ float v_s[2][CH][16];
    __shared__ float db_s[2][256];   // [0..31] dec, [32..63] beta, rest = slop
    __shared__ float o_s[2][CH][16];

    const int b = blockIdx.x, h = b >> 3, cg = b & 7;
    const int tid = threadIdx.x, w = tid >> 6, lane = tid & 63;
    const int cl = w * 4 + (lane >> 4);
    const int rb = (lane & 15) << 3;

    float S[8];
#pragma unroll
    for (int i = 0; i < 8; i++) S[i] = 0.f;

#define STAGE(c, s)                                                                  \
    {                                                                                \
        const int t0_ = (c) * CH;                                                    \
        for (int j = w; j < 35; j += 4) {                                            \
            if (j < 16) {                                                            \
                int u = j * 64 + lane, t = u >> 5, r4 = (u & 31) * 4;                \
                GLL(cv + (size_t)(t0_ + t) * CDIM + h * HD + r4,                     \
                    &q_s[s][0][0] + j * 256);                                        \
            } else if (j < 32) {                                                     \
                int jj = j - 16;                                                     \
                int u = jj * 64 + lane, t = u >> 5, r4 = (u & 31) * 4;               \
                GLL(cv + (size_t)(t0_ + t) * CDIM + NH * HD + h * HD + r4,           \
                    &k_s[s][0][0] + jj * 256);                                       \
            } else if (j < 34) {                                                     \
                int jj = j - 32;                                                     \
                int u = jj * 64 + lane, t = u >> 2, c4 = (u & 3) * 4;                \
                GLL(cv + (size_t)(t0_ + t) * CDIM + 2 * NH * HD + h * HD + cg * 16 + c4, \
                    &v_s[s][0][0] + jj * 256);                                       \
            } else {                                                                 \
                const float* g = (lane < 8)  ? (decT + (size_t)h * T_LEN + t0_ + lane * 4)        \
                               : (lane < 16) ? (betaT + (size_t)h * T_LEN + t0_ + (lane - 8) * 4) \
                                             : (decT + (size_t)h * T_LEN);           \
                GLL(g, &db_s[s][0]);                                                 \
            }                                                                        \
        }                                                                            \
    }

    STAGE(0, 0);
    __syncthreads();
    STAGE(1, 1);

    for (int c = 0; c < T_LEN / CH; c++) {
        const int s = c & 1;
        float4 ka, kb, qa, qb; float vv, dd, bbv;
        {
            const float4* kp = (const float4*)&k_s[s][0][rb];
            ka = kp[0]; kb = kp[1];
            const float4* qp = (const float4*)&q_s[s][0][rb];
            qa = qp[0]; qb = qp[1];
            vv = v_s[s][0][cl];
            dd = db_s[s][0]; bbv = db_s[s][32];
        }
        for (int t = 0; t < CH; t++) {
            int tn = (t + 1 < CH) ? t + 1 : t;
            float4 ka2, kb2, qa2, qb2; float vv2, dd2, bb2;
            {
                const float4* kp = (const float4*)&k_s[s][tn][rb];
                ka2 = kp[0]; kb2 = kp[1];
                const float4* qp = (const float4*)&q_s[s][tn][rb];
                qa2 = qp[0]; qb2 = qp[1];
                vv2 = v_s[s][tn][cl];
                dd2 = db_s[s][tn]; bb2 = db_s[s][32 + tn];
            }
            float part = ((ka.x * S[0] + ka.y * S[1]) + (ka.z * S[2] + ka.w * S[3]))
                       + ((kb.x * S[4] + kb.y * S[5]) + (kb.z * S[6] + kb.w * S[7]));
            float pred = reduce16(part) * dd;
            float uu = bbv * (vv - pred);
            S[0] = fmaf(ka.x, uu, dd * S[0]);
            S[1] = fmaf(ka.y, uu, dd * S[1]);
            S[2] = fmaf(ka.z, uu, dd * S[2]);
            S[3] = fmaf(ka.w, uu, dd * S[3]);
            S[4] = fmaf(kb.x, uu, dd * S[4]);
            S[5] = fmaf(kb.y, uu, dd * S[5]);
            S[6] = fmaf(kb.z, uu, dd * S[6]);
            S[7] = fmaf(kb.w, uu, dd * S[7]);
            float op = ((qa.x * S[0] + qa.y * S[1]) + (qa.z * S[2] + qa.w * S[3]))
                     + ((qb.x * S[4] + qb.y * S[5]) + (qb.z * S[6] + qb.w * S[7]));
            op = reduce16(op);
            if ((lane & 15) == 0) o_s[s][t][cl] = op;
            ka = ka2; kb = kb2; qa = qa2; qb = qb2; vv = vv2; dd = dd2; bbv = bb2;
        }
        __syncthreads();   // drains staging of chunk c+1 and this chunk's o_s writes
        {
            int idx = tid * 2;
            int t = idx >> 4, ci = idx & 15;
            uint32 pv = (uint32)f2bf(o_s[s][t][ci]) | ((uint32)f2bf(o_s[s][t][ci + 1]) << 16);
            *(uint32*)&o16[(size_t)(c * CH + t) * DM + h * HD + cg * 16 + ci] = pv;
        }
        if (c + 2 < T_LEN / CH) STAGE(c + 2, s);
    }
#undef STAGE
}

// ---------------------------------------------------------------------------
// Workspace layout (float offsets), ~117 MB total:
//   cv       [0, 12582912)            fp32; x16 overlays its first 8.4MB
//   u16      [12582912, 18874368)     bf16 (12,582,912 elems)
//   h116     [18874368, 19660800)     bf16
//   decT     [19660800, +32768) ; betaT next 32768
//   wT       [19726336, +9437184)     bf16 weight scratch (seq: WqkvT/gw1T/gw2T/WoT)
//   o16      = wT + 4194304 bf16 elems (coexists with WoT only)
// ---------------------------------------------------------------------------
extern "C" void kernel_launch(void* const* d_in, const int* in_sizes, int n_in,
                              void* d_out, int out_size, void* d_ws, size_t ws_size,
                              hipStream_t stream)
{
    const float* x      = (const float*)d_in[0];
    const float* W_qkv  = (const float*)d_in[1];
    const float* W_ba   = (const float*)d_in[2];
    const float* gen_w1 = (const float*)d_in[3];
    const float* gen_w2 = (const float*)d_in[4];
    const float* gen_b2 = (const float*)d_in[5];
    const float* W_o    = (const float*)d_in[6];
    float* y  = (float*)d_out;
    float* wsf = (float*)d_ws;

    float*  cv    = wsf;
    bf16_t* x16   = (bf16_t*)wsf;
    bf16_t* u16   = (bf16_t*)(wsf + 12582912);
    bf16_t* h116  = (bf16_t*)(wsf + 18874368);
    float*  decT  = wsf + 19660800;
    float*  betaT = wsf + 19693568;
    bf16_t* wT    = (bf16_t*)(wsf + 19726336);
    bf16_t* o16   = wT + 4194304;

    dim3 blk(256);

    // W_qkv^T (bf16) and x (bf16)
    tcast<<<dim3(192, 64), blk, 0, stream>>>(W_qkv, wT, DM, CDIM);
    castk<<<dim3(4096), blk, 0, stream>>>(x, x16, (T_LEN * DM) / 4);
    // u16 = bf16(x @ W_qkv)
    mgemm<1><<<dim3(48, 16), blk, 0, stream>>>(x16, wT, nullptr, u16, T_LEN, CDIM, DM);
    // beta/decay (fp32, transposed [H][T])
    ba_kernel<<<dim3(512), blk, 0, stream>>>(x, W_ba, betaT, decT);
    // gen_w1^T ; h1 = silu(u @ gen_w1) in bf16
    tcast<<<dim3(24, 192), blk, 0, stream>>>(gen_w1, wT, CDIM, GH);
    mgemm<2><<<dim3(6, 16), blk, 0, stream>>>(u16, wT, nullptr, h116, T_LEN, GH, CDIM);
    // gen_w2^T ; cv = silu(conv(u, h1@gen_w2+b2))
    tcast<<<dim3(768, 24), blk, 0, stream>>>(gen_w2, wT, GH, NOUT);
    convgen<<<dim3(192, 16), blk, 0, stream>>>(h116, wT, gen_b2, u16, cv);
    // l2norm q,k in place
    norm_qk<<<dim3(16384), blk, 0, stream>>>(cv);
    // W_o^T (into wT; gw2T dead) then scan -> o16 (disjoint sub-region)
    tcast<<<dim3(64, 64), blk, 0, stream>>>(W_o, wT, DM, DM);
    scan_kernel<<<dim3(128), blk, 0, stream>>>(cv, betaT, decT, o16);
    // y = o @ W_o (fp32 out)
    mgemm<0><<<dim3(16, 16), blk, 0, stream>>>(o16, wT, y, nullptr, T_LEN, DM, DM);
}

// Round 3
// 1277.145 us; speedup vs baseline: 3.4517x; 1.0848x over previous
//
#include <hip/hip_runtime.h>
#include <math.h>

#define T_LEN 2048
#define DM    2048
#define NH    16
#define HD    128
#define CDIM  6144
#define GH    768
#define NOUT  24576
#define CH    16

typedef unsigned short bf16_t;
typedef unsigned int   uint32;
typedef __attribute__((ext_vector_type(8))) short short8;
typedef __attribute__((ext_vector_type(4))) float f32x4;

__device__ __forceinline__ float silu_f(float v) { return v / (1.f + __expf(-v)); }

__device__ __forceinline__ bf16_t f2bf(float f) {
    uint32 u = __float_as_uint(f);
    u = (u + 0x7fff + ((u >> 16) & 1)) >> 16;   // RNE
    return (bf16_t)u;
}
__device__ __forceinline__ float bf2f(bf16_t b) {
    return __uint_as_float(((uint32)b) << 16);
}

// async global->LDS, 16B per lane; LDS dest = wave-uniform base + lane*16
#define GLL(gptr, lptr) \
  __builtin_amdgcn_global_load_lds((const __attribute__((address_space(1))) void*)(gptr), \
                                   (__attribute__((address_space(3))) void*)(lptr), 16, 0, 0)

// ---------------------------------------------------------------------------
// Transpose + cast: W [K][N] fp32 -> Wt [N][K] bf16
// ---------------------------------------------------------------------------
__global__ __launch_bounds__(256)
void tcast(const float* __restrict__ W, bf16_t* __restrict__ Wt, int K, int N)
{
    __shared__ float tile[32][33];
    const int n0 = blockIdx.x * 32, k0 = blockIdx.y * 32;
    const int c = threadIdx.x & 31, r = threadIdx.x >> 5;
#pragma unroll
    for (int i = 0; i < 4; i++)
        tile[r + i * 8][c] = W[(size_t)(k0 + r + i * 8) * N + n0 + c];
    __syncthreads();
#pragma unroll
    for (int i = 0; i < 4; i++)
        Wt[(size_t)(n0 + r + i * 8) * K + k0 + c] = f2bf(tile[c][r + i * 8]);
}

// elementwise fp32 -> bf16 (4 per thread)
__global__ __launch_bounds__(256)
void castk(const float* __restrict__ in, bf16_t* __restrict__ out, int n4)
{
    int i = blockIdx.x * 256 + threadIdx.x;
    if (i >= n4) return;
    float4 v = ((const float4*)in)[i];
    uint2 p;
    p.x = (uint32)f2bf(v.x) | ((uint32)f2bf(v.y) << 16);
    p.y = (uint32)f2bf(v.z) | ((uint32)f2bf(v.w) << 16);
    ((uint2*)out)[i] = p;
}

// ---------------------------------------------------------------------------
// bf16 MFMA GEMM (m97 structure): C[M,N] = A[M,K] @ Bt[N,K]^T
// NPER>0: 1D grid, XCD-swizzled so all 16 M-blocks of one N-tile co-reside
// on one XCD (B slice fetched from HBM ~once, L2 serves the rest).
// EPI: 0 = fp32 store, 1 = bf16 store, 2 = silu + bf16 store
// ---------------------------------------------------------------------------
template<int EPI, int NPER>
__global__ __launch_bounds__(256)
void mgemm(const bf16_t* __restrict__ A, const bf16_t* __restrict__ Bt,
           float* __restrict__ C, bf16_t* __restrict__ C16,
           int M, int N, int K)
{
    __shared__ bf16_t As[4096];
    __shared__ bf16_t Bs[4096];
    const int tid = threadIdx.x;
    const int lane = tid & 63, w = tid >> 6;
    const int quad = lane >> 4, tl = lane & 15;
    int bm0, bn0;
    if (NPER == 0) { bm0 = blockIdx.y * 128; bn0 = blockIdx.x * 128; }
    else {
        int bx = blockIdx.x, xcd = bx & 7, seq = bx >> 3;
        bm0 = (seq & 15) * 128;                 // M fast within XCD group
        bn0 = (xcd * NPER + (seq >> 4)) * 128;
    }
    const int wm = (w >> 1) * 64, wn = (w & 1) * 64;

    const bf16_t* a0 = A  + (size_t)(bm0 + (tid & 127)) * K + ((tid >> 7) << 3);
    const bf16_t* b0 = Bt + (size_t)(bn0 + (tid & 127)) * K + ((tid >> 7) << 3);
    bf16_t* asd0 = &As[w * 512];
    bf16_t* asd1 = &As[2048 + w * 512];
    bf16_t* bsd0 = &Bs[w * 512];
    bf16_t* bsd1 = &Bs[2048 + w * 512];

    f32x4 acc[4][4];
#pragma unroll
    for (int i = 0; i < 4; i++)
#pragma unroll
        for (int j = 0; j < 4; j++) { acc[i][j][0] = 0.f; acc[i][j][1] = 0.f; acc[i][j][2] = 0.f; acc[i][j][3] = 0.f; }

    for (int k0 = 0; k0 < K; k0 += 32) {
        __syncthreads();
        GLL(a0 + k0,      asd0);
        GLL(a0 + k0 + 16, asd1);
        GLL(b0 + k0,      bsd0);
        GLL(b0 + k0 + 16, bsd1);
        __syncthreads();
        short8 af[4], bfr[4];
#pragma unroll
        for (int mt = 0; mt < 4; mt++)
            af[mt] = *(const short8*)&As[(quad * 128 + wm + mt * 16 + tl) * 8];
#pragma unroll
        for (int nt = 0; nt < 4; nt++)
            bfr[nt] = *(const short8*)&Bs[(quad * 128 + wn + nt * 16 + tl) * 8];
#pragma unroll
        for (int mt = 0; mt < 4; mt++)
#pragma unroll
            for (int nt = 0; nt < 4; nt++)
                acc[mt][nt] = __builtin_amdgcn_mfma_f32_16x16x32_bf16(af[mt], bfr[nt], acc[mt][nt], 0, 0, 0);
    }

#pragma unroll
    for (int mt = 0; mt < 4; mt++) {
        int rbase = bm0 + wm + mt * 16 + quad * 4;
#pragma unroll
        for (int nt = 0; nt < 4; nt++) {
            int cg = bn0 + wn + nt * 16 + tl;
#pragma unroll
            for (int r = 0; r < 4; r++) {
                float v = acc[mt][nt][r];
                size_t idx = (size_t)(rbase + r) * N + cg;
                if (EPI == 0)      C[idx]   = v;
                else if (EPI == 1) C16[idx] = f2bf(v);
                else               C16[idx] = f2bf(silu_f(v));
            }
        }
    }
}

// ---------------------------------------------------------------------------
// convgen: kern = h1 @ gen_w2 + b2 (MFMA), fused causal W=4 conv + silu.
// XCD-swizzled 1D grid (24 N-tiles per XCD, M fast).
// ---------------------------------------------------------------------------
__global__ __launch_bounds__(256)
void convgen(const bf16_t* __restrict__ A, const bf16_t* __restrict__ Bt,
             const float* __restrict__ b2, const bf16_t* __restrict__ u16c,
             float* __restrict__ cvout)
{
    const int K = GH;
    __shared__ bf16_t As[4096];
    __shared__ bf16_t Bs[4096];
    const int tid = threadIdx.x;
    const int lane = tid & 63, w = tid >> 6;
    const int quad = lane >> 4, tl = lane & 15;
    const int bx = blockIdx.x, xcd = bx & 7, seq = bx >> 3;
    const int bm0 = (seq & 15) * 128;
    const int bn0 = (xcd * 24 + (seq >> 4)) * 128;
    const int wm = (w >> 1) * 64, wn = (w & 1) * 64;

    const bf16_t* a0 = A  + (size_t)(bm0 + (tid & 127)) * K + ((tid >> 7) << 3);
    const bf16_t* b0 = Bt + (size_t)(bn0 + (tid & 127)) * K + ((tid >> 7) << 3);
    bf16_t* asd0 = &As[w * 512];
    bf16_t* asd1 = &As[2048 + w * 512];
    bf16_t* bsd0 = &Bs[w * 512];
    bf16_t* bsd1 = &Bs[2048 + w * 512];

    f32x4 acc[4][4];
#pragma unroll
    for (int i = 0; i < 4; i++)
#pragma unroll
        for (int j = 0; j < 4; j++) { acc[i][j][0] = 0.f; acc[i][j][1] = 0.f; acc[i][j][2] = 0.f; acc[i][j][3] = 0.f; }

    for (int k0 = 0; k0 < K; k0 += 32) {
        __syncthreads();
        GLL(a0 + k0,      asd0);
        GLL(a0 + k0 + 16, asd1);
        GLL(b0 + k0,      bsd0);
        GLL(b0 + k0 + 16, bsd1);
        __syncthreads();
        short8 af[4], bfr[4];
#pragma unroll
        for (int mt = 0; mt < 4; mt++)
            af[mt] = *(const short8*)&As[(quad * 128 + wm + mt * 16 + tl) * 8];
#pragma unroll
        for (int nt = 0; nt < 4; nt++)
            bfr[nt] = *(const short8*)&Bs[(quad * 128 + wn + nt * 16 + tl) * 8];
#pragma unroll
        for (int mt = 0; mt < 4; mt++)
#pragma unroll
            for (int nt = 0; nt < 4; nt++)
                acc[mt][nt] = __builtin_amdgcn_mfma_f32_16x16x32_bf16(af[mt], bfr[nt], acc[mt][nt], 0, 0, 0);
    }

#pragma unroll
    for (int nt = 0; nt < 4; nt++) {
        int n = bn0 + wn + nt * 16 + tl;
        int d = n >> 2, wi = n & 3;
        float b2v = b2[n];
#pragma unroll
        for (int mt = 0; mt < 4; mt++) {
            int rbase = bm0 + wm + mt * 16 + quad * 4;
#pragma unroll
            for (int r = 0; r < 4; r++) {
                int t = rbase + r;
                float kern = acc[mt][nt][r] + b2v;
                int tr = t - 3 + wi;
                float uval = (tr >= 0) ? bf2f(u16c[(size_t)tr * CDIM + d]) : 0.f;
                float p = kern * uval;
                p += __shfl_xor(p, 1);
                p += __shfl_xor(p, 2);
                if ((tl & 3) == 0) cvout[(size_t)t * CDIM + d] = silu_f(p);
            }
        }
    }
}

// ---------------------------------------------------------------------------
// ba: grid 256 x 256 threads; thread (t = b*8 + tid/32, c = tid&31).
// Broadcast float4 x reads (L1), coalesced W_ba column reads (L2-resident).
// ---------------------------------------------------------------------------
__global__ __launch_bounds__(256)
void ba_kernel(const float* __restrict__ x, const float* __restrict__ Wba,
               float* __restrict__ betaT, float* __restrict__ decT)
{
    const int t = blockIdx.x * 8 + (threadIdx.x >> 5);
    const int c = threadIdx.x & 31;
    const float* xr = x + (size_t)t * DM;
    float acc = 0.f;
#pragma unroll 4
    for (int k0 = 0; k0 < DM; k0 += 4) {
        float4 xv = *(const float4*)&xr[k0];
        acc = fmaf(xv.x, Wba[(k0 + 0) * 32 + c], acc);
        acc = fmaf(xv.y, Wba[(k0 + 1) * 32 + c], acc);
        acc = fmaf(xv.z, Wba[(k0 + 2) * 32 + c], acc);
        acc = fmaf(xv.w, Wba[(k0 + 3) * 32 + c], acc);
    }
    float val = 1.f / (1.f + __expf((c < 16) ? -acc : acc));
    if (c < 16) betaT[(size_t)c * T_LEN + t] = val;
    else        decT[(size_t)(c - 16) * T_LEN + t] = val;
}

// ---------------------------------------------------------------------------
// In-place l2norm of q,k rows (q also * DK^-0.5). One wave per 128-row.
// ---------------------------------------------------------------------------
__global__ __launch_bounds__(256)
void norm_qk(float* __restrict__ cv)
{
    int gw = (blockIdx.x * 256 + threadIdx.x) >> 6;
    int lane = threadIdx.x & 63;
    int t = gw >> 5, rest = gw & 31, sec = rest >> 4, h = rest & 15;
    float* p = cv + (size_t)t * CDIM + sec * (NH * HD) + h * HD;
    float x0 = p[lane], x1 = p[lane + 64];
    float ss = x0 * x0 + x1 * x1;
#pragma unroll
    for (int m = 32; m >= 1; m >>= 1) ss += __shfl_xor(ss, m);
    float sc = rsqrtf(ss + 1e-6f);
    if (sec == 0) sc *= 0.08838834764831845f;
    p[lane] = x0 * sc; p[lane + 64] = x1 * sc;
}

// ---------------------------------------------------------------------------
// Gated delta-rule scan. 256 blocks x 128 threads: block = (head, 8 columns).
// q/k staged per CH=16 chunk in conflict-free [t][half][lane][4] layout
// (b128 reads hit banks 4*tl -> 2-way aliasing = free). v as [t][8col]
// (1 GLL/chunk), dec/beta packed (1 GLL/chunk). Double-buffered.
// ---------------------------------------------------------------------------
template<int CTRL>
__device__ __forceinline__ float dpp_add(float x) {
    int y = __builtin_amdgcn_mov_dpp(__float_as_int(x), CTRL, 0xF, 0xF, true);
    return x + __int_as_float(y);
}
__device__ __forceinline__ float reduce16(float x) {
    x = dpp_add<0x128>(x);
    x = dpp_add<0x124>(x);
    x = dpp_add<0x122>(x);
    x = dpp_add<0x121>(x);
    return x;
}

__global__ __launch_bounds__(128)
void scan_kernel(const float* __restrict__ cv, const float* __restrict__ betaT,
                 const float* __restrict__ decT, bf16_t* __restrict__ o16)
{
    __shared__ float q_s[2][CH][128];
    __shared__ float k_s[2][CH][128];
    __shared__ float v_s[2][CH][8];
    __shared__ float db_s[2][32];
    __shared__ float o_s[2][CH][8];

    const int b = blockIdx.x, h = b >> 4, cg = b & 15;
    const int tid = threadIdx.x, w = tid >> 6, lane = tid & 63;
    const int cl = w * 4 + (lane >> 4);
    const int tl = lane & 15;

    const float* qbp = cv + h * HD;
    const float* kbp = cv + NH * HD + h * HD;
    const float* vbp = cv + 2 * NH * HD + h * HD + cg * 8;

    float S[8];
#pragma unroll
    for (int i = 0; i < 8; i++) S[i] = 0.f;

    // swizzled stage: GLL j covers rows 2j,2j+1; lane -> (t, half, tl2)
#define STAGE(c, s)                                                            \
    {                                                                          \
        const int t0_ = (c) * CH;                                              \
        const int tt_ = 2 * (lane >> 5);                                       \
        const int local_ = lane & 31;                                          \
        const int off_ = (local_ >> 4) * 4 + (local_ & 15) * 8;                \
        for (int jj = 0; jj < 4; jj++) {                                       \
            int j = jj * 2 + w;                                                \
            size_t go = (size_t)(t0_ + 2 * j + (tt_ >> 1)) * CDIM + off_;      \
            GLL(qbp + go, &q_s[s][2 * j][0]);                                  \
            GLL(kbp + go, &k_s[s][2 * j][0]);                                  \
        }                                                                      \
        if (w == 0) {                                                          \
            if (lane < 32)                                                     \
                GLL(vbp + (size_t)(t0_ + (lane >> 1)) * CDIM + (lane & 1) * 4, \
                    &v_s[s][0][0]);                                            \
        } else if (lane < 8) {                                                 \
            const float* g = (lane < 4)                                        \
                ? (decT + (size_t)h * T_LEN + t0_ + lane * 4)                  \
                : (betaT + (size_t)h * T_LEN + t0_ + (lane - 4) * 4);          \
            GLL(g, &db_s[s][0]);                                               \
        }                                                                      \
    }

#define LOADR(i, s, t)                                                 \
    {                                                                  \
        kA[i] = *(const float4*)&k_s[s][t][tl * 4];                    \
        kB[i] = *(const float4*)&k_s[s][t][64 + tl * 4];               \
        qA[i] = *(const float4*)&q_s[s][t][tl * 4];                    \
        qB[i] = *(const float4*)&q_s[s][t][64 + tl * 4];               \
        vv[i] = v_s[s][t][cl];                                         \
        dd[i] = db_s[s][t];                                            \
        bbv[i] = db_s[s][16 + t];                                      \
    }

#define STEP(i, s, t)                                                              \
    {                                                                              \
        float part = ((kA[i].x * S[0] + kA[i].y * S[1]) + (kA[i].z * S[2] + kA[i].w * S[3])) \
                   + ((kB[i].x * S[4] + kB[i].y * S[5]) + (kB[i].z * S[6] + kB[i].w * S[7])); \
        float pred = reduce16(part) * dd[i];                                       \
        float uu = bbv[i] * (vv[i] - pred);                                        \
        S[0] = fmaf(kA[i].x, uu, dd[i] * S[0]);                                    \
        S[1] = fmaf(kA[i].y, uu, dd[i] * S[1]);                                    \
        S[2] = fmaf(kA[i].z, uu, dd[i] * S[2]);                                    \
        S[3] = fmaf(kA[i].w, uu, dd[i] * S[3]);                                    \
        S[4] = fmaf(kB[i].x, uu, dd[i] * S[4]);                                    \
        S[5] = fmaf(kB[i].y, uu, dd[i] * S[5]);                                    \
        S[6] = fmaf(kB[i].z, uu, dd[i] * S[6]);                                    \
        S[7] = fmaf(kB[i].w, uu, dd[i] * S[7]);                                    \
        float op = ((qA[i].x * S[0] + qA[i].y * S[1]) + (qA[i].z * S[2] + qA[i].w * S[3])) \
                 + ((qB[i].x * S[4] + qB[i].y * S[5]) + (qB[i].z * S[6] + qB[i].w * S[7])); \
        op = reduce16(op);                                                         \
        if (tl == 0) o_s[s][t][cl] = op;                                           \
    }

    STAGE(0, 0);
    __syncthreads();
    STAGE(1, 1);

    float4 kA[2], kB[2], qA[2], qB[2];
    float vv[2], dd[2], bbv[2];

    for (int c = 0; c < T_LEN / CH; c++) {
        const int s = c & 1;
        LOADR(0, s, 0);
#pragma unroll
        for (int t = 0; t < CH; t++) {
            const int i = t & 1;
            if (t + 1 < CH) LOADR(i ^ 1, s, t + 1);
            STEP(i, s, t);
        }
        __syncthreads();   // drains chunk c+1 staging; all waves done with buf s
        {
            if (tid < 64) {
                int t = tid >> 2, c2 = (tid & 3) * 2;
                uint32 pv = (uint32)f2bf(o_s[s][t][c2]) | ((uint32)f2bf(o_s[s][t][c2 + 1]) << 16);
                *(uint32*)&o16[(size_t)(c * CH + t) * DM + h * HD + cg * 8 + c2] = pv;
            }
        }
        if (c + 2 < T_LEN / CH) STAGE(c + 2, s);
    }
#undef STAGE
#undef LOADR
#undef STEP
}

// ---------------------------------------------------------------------------
// Workspace layout (float offsets), ~117 MB total (same as R1):
//   cv [0, 12582912) fp32 (x16 overlays head) | u16 | h116 | decT | betaT |
//   wT (weight scratch) | o16 = wT + 4194304 bf16 elems
// ---------------------------------------------------------------------------
extern "C" void kernel_launch(void* const* d_in, const int* in_sizes, int n_in,
                              void* d_out, int out_size, void* d_ws, size_t ws_size,
                              hipStream_t stream)
{
    const float* x      = (const float*)d_in[0];
    const float* W_qkv  = (const float*)d_in[1];
    const float* W_ba   = (const float*)d_in[2];
    const float* gen_w1 = (const float*)d_in[3];
    const float* gen_w2 = (const float*)d_in[4];
    const float* gen_b2 = (const float*)d_in[5];
    const float* W_o    = (const float*)d_in[6];
    float* y  = (float*)d_out;
    float* wsf = (float*)d_ws;

    float*  cv    = wsf;
    bf16_t* x16   = (bf16_t*)wsf;
    bf16_t* u16   = (bf16_t*)(wsf + 12582912);
    bf16_t* h116  = (bf16_t*)(wsf + 18874368);
    float*  decT  = wsf + 19660800;
    float*  betaT = wsf + 19693568;
    bf16_t* wT    = (bf16_t*)(wsf + 19726336);
    bf16_t* o16   = wT + 4194304;

    dim3 blk(256);

    tcast<<<dim3(192, 64), blk, 0, stream>>>(W_qkv, wT, DM, CDIM);
    castk<<<dim3(4096), blk, 0, stream>>>(x, x16, (T_LEN * DM) / 4);
    // u16 = bf16(x @ W_qkv) — XCD-swizzled (48 N-tiles = 8 XCD * 6)
    mgemm<1, 6><<<dim3(768), blk, 0, stream>>>(x16, wT, nullptr, u16, T_LEN, CDIM, DM);
    ba_kernel<<<dim3(256), blk, 0, stream>>>(x, W_ba, betaT, decT);
    tcast<<<dim3(24, 192), blk, 0, stream>>>(gen_w1, wT, CDIM, GH);
    mgemm<2, 0><<<dim3(6, 16), blk, 0, stream>>>(u16, wT, nullptr, h116, T_LEN, GH, CDIM);
    tcast<<<dim3(768, 24), blk, 0, stream>>>(gen_w2, wT, GH, NOUT);
    // fused conv — XCD-swizzled (192 N-tiles = 8 XCD * 24)
    convgen<<<dim3(3072), blk, 0, stream>>>(h116, wT, gen_b2, u16, cv);
    norm_qk<<<dim3(16384), blk, 0, stream>>>(cv);
    tcast<<<dim3(64, 64), blk, 0, stream>>>(W_o, wT, DM, DM);
    scan_kernel<<<dim3(256), dim3(128), 0, stream>>>(cv, betaT, decT, o16);
    // y = o @ W_o — XCD-swizzled (16 N-tiles = 8 XCD * 2)
    mgemm<0, 2><<<dim3(256), blk, 0, stream>>>(o16, wT, y, nullptr, T_LEN, DM, DM);
}

// Round 4
// 1158.673 us; speedup vs baseline: 3.8046x; 1.1022x over previous
//
#include <hip/hip_runtime.h>
#include <math.h>

#define T_LEN 2048
#define DM    2048
#define NH    16
#define HD    128
#define CDIM  6144
#define GH    768
#define NOUT  24576

typedef unsigned short bf16_t;
typedef unsigned int   uint32;
typedef __attribute__((ext_vector_type(8))) short short8;
typedef __attribute__((ext_vector_type(4))) float f32x4;

__device__ __forceinline__ float silu_f(float v) { return v / (1.f + __expf(-v)); }

__device__ __forceinline__ bf16_t f2bf(float f) {
    uint32 u = __float_as_uint(f);
    u = (u + 0x7fff + ((u >> 16) & 1)) >> 16;   // RNE
    return (bf16_t)u;
}
__device__ __forceinline__ float bf2f(bf16_t b) {
    return __uint_as_float(((uint32)b) << 16);
}
__device__ __forceinline__ uint32 pack2f(float a, float b) {
    return (uint32)f2bf(a) | ((uint32)f2bf(b) << 16);
}

// async global->LDS, 16B per lane; LDS dest = wave-uniform base + lane*16
#define GLL(gptr, lptr) \
  __builtin_amdgcn_global_load_lds((const __attribute__((address_space(1))) void*)(gptr), \
                                   (__attribute__((address_space(3))) void*)(lptr), 16, 0, 0)

// ---------------------------------------------------------------------------
// Transpose + cast: W [K][N] fp32 -> Wt [N][K] bf16
// ---------------------------------------------------------------------------
__global__ __launch_bounds__(256)
void tcast(const float* __restrict__ W, bf16_t* __restrict__ Wt, int K, int N)
{
    __shared__ float tile[32][33];
    const int n0 = blockIdx.x * 32, k0 = blockIdx.y * 32;
    const int c = threadIdx.x & 31, r = threadIdx.x >> 5;
#pragma unroll
    for (int i = 0; i < 4; i++)
        tile[r + i * 8][c] = W[(size_t)(k0 + r + i * 8) * N + n0 + c];
    __syncthreads();
#pragma unroll
    for (int i = 0; i < 4; i++)
        Wt[(size_t)(n0 + r + i * 8) * K + k0 + c] = f2bf(tile[c][r + i * 8]);
}

// elementwise fp32 -> bf16 (4 per thread)
__global__ __launch_bounds__(256)
void castk(const float* __restrict__ in, bf16_t* __restrict__ out, int n4)
{
    int i = blockIdx.x * 256 + threadIdx.x;
    if (i >= n4) return;
    float4 v = ((const float4*)in)[i];
    uint2 p;
    p.x = pack2f(v.x, v.y);
    p.y = pack2f(v.z, v.w);
    ((uint2*)out)[i] = p;
}

// ---------------------------------------------------------------------------
// bf16 MFMA GEMM (m97 structure): C[M,N] = A[M,K] @ Bt[N,K]^T
// ---------------------------------------------------------------------------
template<int EPI, int NPER>
__global__ __launch_bounds__(256)
void mgemm(const bf16_t* __restrict__ A, const bf16_t* __restrict__ Bt,
           float* __restrict__ C, bf16_t* __restrict__ C16,
           int M, int N, int K)
{
    __shared__ bf16_t As[4096];
    __shared__ bf16_t Bs[4096];
    const int tid = threadIdx.x;
    const int lane = tid & 63, w = tid >> 6;
    const int quad = lane >> 4, tl = lane & 15;
    int bm0, bn0;
    if (NPER == 0) { bm0 = blockIdx.y * 128; bn0 = blockIdx.x * 128; }
    else {
        int bx = blockIdx.x, xcd = bx & 7, seq = bx >> 3;
        bm0 = (seq & 15) * 128;
        bn0 = (xcd * NPER + (seq >> 4)) * 128;
    }
    const int wm = (w >> 1) * 64, wn = (w & 1) * 64;

    const bf16_t* a0 = A  + (size_t)(bm0 + (tid & 127)) * K + ((tid >> 7) << 3);
    const bf16_t* b0 = Bt + (size_t)(bn0 + (tid & 127)) * K + ((tid >> 7) << 3);
    bf16_t* asd0 = &As[w * 512];
    bf16_t* asd1 = &As[2048 + w * 512];
    bf16_t* bsd0 = &Bs[w * 512];
    bf16_t* bsd1 = &Bs[2048 + w * 512];

    f32x4 acc[4][4];
#pragma unroll
    for (int i = 0; i < 4; i++)
#pragma unroll
        for (int j = 0; j < 4; j++) { acc[i][j][0] = 0.f; acc[i][j][1] = 0.f; acc[i][j][2] = 0.f; acc[i][j][3] = 0.f; }

    for (int k0 = 0; k0 < K; k0 += 32) {
        __syncthreads();
        GLL(a0 + k0,      asd0);
        GLL(a0 + k0 + 16, asd1);
        GLL(b0 + k0,      bsd0);
        GLL(b0 + k0 + 16, bsd1);
        __syncthreads();
        short8 af[4], bfr[4];
#pragma unroll
        for (int mt = 0; mt < 4; mt++)
            af[mt] = *(const short8*)&As[(quad * 128 + wm + mt * 16 + tl) * 8];
#pragma unroll
        for (int nt = 0; nt < 4; nt++)
            bfr[nt] = *(const short8*)&Bs[(quad * 128 + wn + nt * 16 + tl) * 8];
#pragma unroll
        for (int mt = 0; mt < 4; mt++)
#pragma unroll
            for (int nt = 0; nt < 4; nt++)
                acc[mt][nt] = __builtin_amdgcn_mfma_f32_16x16x32_bf16(af[mt], bfr[nt], acc[mt][nt], 0, 0, 0);
    }

#pragma unroll
    for (int mt = 0; mt < 4; mt++) {
        int rbase = bm0 + wm + mt * 16 + quad * 4;
#pragma unroll
        for (int nt = 0; nt < 4; nt++) {
            int cg = bn0 + wn + nt * 16 + tl;
#pragma unroll
            for (int r = 0; r < 4; r++) {
                float v = acc[mt][nt][r];
                size_t idx = (size_t)(rbase + r) * N + cg;
                if (EPI == 0)      C[idx]   = v;
                else if (EPI == 1) C16[idx] = f2bf(v);
                else               C16[idx] = f2bf(silu_f(v));
            }
        }
    }
}

// ---------------------------------------------------------------------------
// convgen: kern = h1 @ gen_w2 + b2 (MFMA), fused causal W=4 conv + silu.
// ---------------------------------------------------------------------------
__global__ __launch_bounds__(256)
void convgen(const bf16_t* __restrict__ A, const bf16_t* __restrict__ Bt,
             const float* __restrict__ b2, const bf16_t* __restrict__ u16c,
             float* __restrict__ cvout)
{
    const int K = GH;
    __shared__ bf16_t As[4096];
    __shared__ bf16_t Bs[4096];
    const int tid = threadIdx.x;
    const int lane = tid & 63, w = tid >> 6;
    const int quad = lane >> 4, tl = lane & 15;
    const int bx = blockIdx.x, xcd = bx & 7, seq = bx >> 3;
    const int bm0 = (seq & 15) * 128;
    const int bn0 = (xcd * 24 + (seq >> 4)) * 128;
    const int wm = (w >> 1) * 64, wn = (w & 1) * 64;

    const bf16_t* a0 = A  + (size_t)(bm0 + (tid & 127)) * K + ((tid >> 7) << 3);
    const bf16_t* b0 = Bt + (size_t)(bn0 + (tid & 127)) * K + ((tid >> 7) << 3);
    bf16_t* asd0 = &As[w * 512];
    bf16_t* asd1 = &As[2048 + w * 512];
    bf16_t* bsd0 = &Bs[w * 512];
    bf16_t* bsd1 = &Bs[2048 + w * 512];

    f32x4 acc[4][4];
#pragma unroll
    for (int i = 0; i < 4; i++)
#pragma unroll
        for (int j = 0; j < 4; j++) { acc[i][j][0] = 0.f; acc[i][j][1] = 0.f; acc[i][j][2] = 0.f; acc[i][j][3] = 0.f; }

    for (int k0 = 0; k0 < K; k0 += 32) {
        __syncthreads();
        GLL(a0 + k0,      asd0);
        GLL(a0 + k0 + 16, asd1);
        GLL(b0 + k0,      bsd0);
        GLL(b0 + k0 + 16, bsd1);
        __syncthreads();
        short8 af[4], bfr[4];
#pragma unroll
        for (int mt = 0; mt < 4; mt++)
            af[mt] = *(const short8*)&As[(quad * 128 + wm + mt * 16 + tl) * 8];
#pragma unroll
        for (int nt = 0; nt < 4; nt++)
            bfr[nt] = *(const short8*)&Bs[(quad * 128 + wn + nt * 16 + tl) * 8];
#pragma unroll
        for (int mt = 0; mt < 4; mt++)
#pragma unroll
            for (int nt = 0; nt < 4; nt++)
                acc[mt][nt] = __builtin_amdgcn_mfma_f32_16x16x32_bf16(af[mt], bfr[nt], acc[mt][nt], 0, 0, 0);
    }

#pragma unroll
    for (int nt = 0; nt < 4; nt++) {
        int n = bn0 + wn + nt * 16 + tl;
        int d = n >> 2, wi = n & 3;
        float b2v = b2[n];
#pragma unroll
        for (int mt = 0; mt < 4; mt++) {
            int rbase = bm0 + wm + mt * 16 + quad * 4;
#pragma unroll
            for (int r = 0; r < 4; r++) {
                int t = rbase + r;
                float kern = acc[mt][nt][r] + b2v;
                int tr = t - 3 + wi;
                float uval = (tr >= 0) ? bf2f(u16c[(size_t)tr * CDIM + d]) : 0.f;
                float p = kern * uval;
                p += __shfl_xor(p, 1);
                p += __shfl_xor(p, 2);
                if ((tl & 3) == 0) cvout[(size_t)t * CDIM + d] = silu_f(p);
            }
        }
    }
}

// ---------------------------------------------------------------------------
// ba: beta=sigmoid(b), decay=sigmoid(-a); outputs transposed [H][T]
// ---------------------------------------------------------------------------
__global__ __launch_bounds__(256)
void ba_kernel(const float* __restrict__ x, const float* __restrict__ Wba,
               float* __restrict__ betaT, float* __restrict__ decT)
{
    const int t = blockIdx.x * 8 + (threadIdx.x >> 5);
    const int c = threadIdx.x & 31;
    const float* xr = x + (size_t)t * DM;
    float acc = 0.f;
#pragma unroll 4
    for (int k0 = 0; k0 < DM; k0 += 4) {
        float4 xv = *(const float4*)&xr[k0];
        acc = fmaf(xv.x, Wba[(k0 + 0) * 32 + c], acc);
        acc = fmaf(xv.y, Wba[(k0 + 1) * 32 + c], acc);
        acc = fmaf(xv.z, Wba[(k0 + 2) * 32 + c], acc);
        acc = fmaf(xv.w, Wba[(k0 + 3) * 32 + c], acc);
    }
    float val = 1.f / (1.f + __expf((c < 16) ? -acc : acc));
    if (c < 16) betaT[(size_t)c * T_LEN + t] = val;
    else        decT[(size_t)(c - 16) * T_LEN + t] = val;
}

// ---------------------------------------------------------------------------
// In-place l2norm of q,k rows (q also * DK^-0.5). One wave per 128-row.
// ---------------------------------------------------------------------------
__global__ __launch_bounds__(256)
void norm_qk(float* __restrict__ cv)
{
    int gw = (blockIdx.x * 256 + threadIdx.x) >> 6;
    int lane = threadIdx.x & 63;
    int t = gw >> 5, rest = gw & 31, sec = rest >> 4, h = rest & 15;
    float* p = cv + (size_t)t * CDIM + sec * (NH * HD) + h * HD;
    float x0 = p[lane], x1 = p[lane + 64];
    float ss = x0 * x0 + x1 * x1;
#pragma unroll
    for (int m = 32; m >= 1; m >>= 1) ss += __shfl_xor(ss, m);
    float sc = rsqrtf(ss + 1e-6f);
    if (sec == 0) sc *= 0.08838834764831845f;
    p[lane] = x0 * sc; p[lane + 64] = x1 * sc;
}

// ===========================================================================
// Chunked gated delta rule (UT transform), L = 64.
//
// Per chunk (log-decay c_t = cumsum(log dec), all exp args <= 0):
//   A[s][r] = beta_s e^{c_s-c_r} (k_s.k_r)  (s>r)       [strictly lower]
//   solve (I+A) u = b,  b = beta*v  -  (beta e^{c} k) S0
//     => u = U1 - W S0,  U1 = T(beta v), W = T(beta e^c k),  T=(I+A)^{-1}
//   o_t = e^{c_t} q_t S0 + sum_{s<=t} e^{c_t-c_s}(q_t.k_s) u_s   (D matrix)
//   S_L = e^{c_63} S0 + sum_s e^{c_63-c_s} k_s u_s^T             (KhatT)
//
// Phase 1: 512 blocks (h,c) in parallel: KK^T/QK^T via split-bf16 MFMA
// (hi/lo 2-term, fp32-class precision), fwd substitution in registers,
// store W[64][128], U1T[128][64], KhatT[128][64], D[64][64] (bf16), cs (f32).
// Phase 2: 32 blocks (h, dv-half), serial over 32 chunks; state Z=S^T kept
// in fp32 MFMA accumulators; bf16 copy in LDS for operand reads.
// ===========================================================================
__global__ __launch_bounds__(256)
void dr_phase1(const float* __restrict__ cv, const float* __restrict__ decT,
               const float* __restrict__ betaT,
               bf16_t* __restrict__ P_W, bf16_t* __restrict__ P_U1T,
               bf16_t* __restrict__ P_KT, bf16_t* __restrict__ P_D,
               float* __restrict__ P_cs)
{
    __shared__ unsigned short khl[2][64 * 136];   // [hi/lo][s][dk], stride 136
    __shared__ float A_ls[64 * 68];               // A[s][r], stride 68
    __shared__ float csL[64], betaL[64], eaL[64], ebL[64];

    const int ch = blockIdx.x, h = ch >> 5, c = ch & 31;
    const int t0 = c * 64;
    const int tid = threadIdx.x, w = tid >> 6, lane = tid & 63;
    const int quad = lane >> 4, tl = lane & 15;

    const float* kg = cv + (size_t)t0 * CDIM + NH * HD + h * HD;
    const float* qg = cv + (size_t)t0 * CDIM + h * HD;
    const float* vg = cv + (size_t)t0 * CDIM + 2 * NH * HD + h * HD;

    // --- stage k hi/lo into LDS ---
    uint32* kh32 = (uint32*)&khl[0][0];
    uint32* kl32 = (uint32*)&khl[1][0];
#pragma unroll
    for (int i = 0; i < 8; i++) {
        int idx = tid + 256 * i;            // 2048 float4 total
        int t = idx >> 5, q4 = (idx & 31) * 4;
        float4 v = *(const float4*)&kg[(size_t)t * CDIM + q4];
        bf16_t h0 = f2bf(v.x), h1 = f2bf(v.y), h2 = f2bf(v.z), h3 = f2bf(v.w);
        int b2 = (t * 136 + q4) >> 1;
        kh32[b2]     = (uint32)h0 | ((uint32)h1 << 16);
        kh32[b2 + 1] = (uint32)h2 | ((uint32)h3 << 16);
        kl32[b2]     = pack2f(v.x - bf2f(h0), v.y - bf2f(h1));
        kl32[b2 + 1] = pack2f(v.z - bf2f(h2), v.w - bf2f(h3));
    }
    // --- cumulative log decay, beta, exp tables (wave 0 lanes 0..63) ---
    if (tid < 64) {
        float dec = decT[(size_t)h * T_LEN + t0 + tid];
        float csum = __logf(dec);
#pragma unroll
        for (int off = 1; off < 64; off <<= 1) {
            float o = __shfl_up(csum, off);
            if (tid >= off) csum += o;
        }
        csL[tid]   = csum;
        eaL[tid]   = __expf(csum);
        betaL[tid] = betaT[(size_t)h * T_LEN + t0 + tid];
        float c63 = __shfl(csum, 63);
        ebL[tid]  = __expf(c63 - csum);
    }
    __syncthreads();

    // --- X fragments (per-wave rows 16w..16w+15) from global, split hi/lo ---
    short8 xkh[4], xkl[4], xqh[4], xql[4];
    {
        int row = 16 * w + tl;
#pragma unroll
        for (int kk = 0; kk < 4; kk++) {
            const float* kp = &kg[(size_t)row * CDIM + 32 * kk + 8 * quad];
            const float* qp = &qg[(size_t)row * CDIM + 32 * kk + 8 * quad];
            float kv[8], qv[8];
            *(float4*)&kv[0] = *(const float4*)kp;  *(float4*)&kv[4] = *(const float4*)(kp + 4);
            *(float4*)&qv[0] = *(const float4*)qp;  *(float4*)&qv[4] = *(const float4*)(qp + 4);
#pragma unroll
            for (int j = 0; j < 8; j++) {
                bf16_t hh = f2bf(kv[j]);
                xkh[kk][j] = (short)hh;
                xkl[kk][j] = (short)f2bf(kv[j] - bf2f(hh));
                bf16_t qh = f2bf(qv[j]);
                xqh[kk][j] = (short)qh;
                xql[kk][j] = (short)f2bf(qv[j] - bf2f(qh));
            }
        }
    }
    // --- KK^T and QK^T (split-bf16, 2-term) ---
    f32x4 aK[4], aQ[4];
#pragma unroll
    for (int j = 0; j < 4; j++)
#pragma unroll
        for (int r = 0; r < 4; r++) { aK[j][r] = 0.f; aQ[j][r] = 0.f; }
#pragma unroll
    for (int tj = 0; tj < 4; tj++) {
#pragma unroll
        for (int kk = 0; kk < 4; kk++) {
            int yoff = (16 * tj + tl) * 136 + 32 * kk + 8 * quad;
            short8 yh = *(const short8*)&khl[0][yoff];
            short8 yl = *(const short8*)&khl[1][yoff];
            aK[tj] = __builtin_amdgcn_mfma_f32_16x16x32_bf16(xkh[kk], yh, aK[tj], 0, 0, 0);
            aK[tj] = __builtin_amdgcn_mfma_f32_16x16x32_bf16(xkh[kk], yl, aK[tj], 0, 0, 0);
            aK[tj] = __builtin_amdgcn_mfma_f32_16x16x32_bf16(xkl[kk], yh, aK[tj], 0, 0, 0);
            aQ[tj] = __builtin_amdgcn_mfma_f32_16x16x32_bf16(xqh[kk], yh, aQ[tj], 0, 0, 0);
            aQ[tj] = __builtin_amdgcn_mfma_f32_16x16x32_bf16(xqh[kk], yl, aQ[tj], 0, 0, 0);
            aQ[tj] = __builtin_amdgcn_mfma_f32_16x16x32_bf16(xql[kk], yh, aQ[tj], 0, 0, 0);
        }
    }
    // --- epilogue: A (LDS, fp32) and D (global, bf16) ---
    {
        bf16_t* gD = P_D + (size_t)ch * 4096;
#pragma unroll
        for (int tj = 0; tj < 4; tj++) {
#pragma unroll
            for (int r = 0; r < 4; r++) {
                int s  = 16 * w + 4 * quad + r;     // row
                int rr = 16 * tj + tl;              // col
                float e = __expf(csL[s] - csL[rr]);
                A_ls[s * 68 + rr] = (s > rr) ? betaL[s] * e * aK[tj][r] : 0.f;
                gD[s * 64 + rr] = (s >= rr) ? f2bf(e * aQ[tj][r]) : (bf16_t)0;
            }
        }
    }
    __syncthreads();

    // --- forward substitution: (I+A) u = b, 256 RHS columns ---
    float bb[64];
    if (tid < 128) {
        int j = tid;
#pragma unroll
        for (int s = 0; s < 64; s++) bb[s] = betaL[s] * vg[(size_t)s * CDIM + j];
    } else {
        int dk = tid - 128;
#pragma unroll
        for (int s = 0; s < 64; s++)
            bb[s] = betaL[s] * eaL[s] * (bf2f(khl[0][s * 136 + dk]) + bf2f(khl[1][s * 136 + dk]));
    }
#pragma unroll
    for (int r4 = 0; r4 < 64; r4 += 4) {
        float u0 = bb[r4];
        float u1 = bb[r4 + 1] - A_ls[(r4 + 1) * 68 + r4] * u0;
        float u2 = bb[r4 + 2] - A_ls[(r4 + 2) * 68 + r4] * u0 - A_ls[(r4 + 2) * 68 + r4 + 1] * u1;
        float u3 = bb[r4 + 3] - A_ls[(r4 + 3) * 68 + r4] * u0 - A_ls[(r4 + 3) * 68 + r4 + 1] * u1
                              - A_ls[(r4 + 3) * 68 + r4 + 2] * u2;
        bb[r4] = u0; bb[r4 + 1] = u1; bb[r4 + 2] = u2; bb[r4 + 3] = u3;
#pragma unroll
        for (int s = r4 + 4; s < 64; s++) {
            float4 a4 = *(const float4*)&A_ls[s * 68 + r4];
            bb[s] -= a4.x * u0 + a4.y * u1 + a4.z * u2 + a4.w * u3;
        }
    }
    // --- stores ---
    if (tid < 128) {   // U1T row j (contiguous 64)
        uint32* gU = (uint32*)(P_U1T + (size_t)ch * 8192) + tid * 32;
#pragma unroll
        for (int i = 0; i < 32; i++) gU[i] = pack2f(bb[2 * i], bb[2 * i + 1]);
    }
    {   // KhatT[dk][s] = e^{c63-cs} k_s[dk]
        int dk = tid >> 1, half = tid & 1;
        uint32* gK = (uint32*)(P_KT + (size_t)ch * 8192);
#pragma unroll
        for (int i = 0; i < 16; i++) {
            int s = half * 32 + 2 * i;
            float v0 = ebL[s]     * (bf2f(khl[0][s * 136 + dk])       + bf2f(khl[1][s * 136 + dk]));
            float v1 = ebL[s + 1] * (bf2f(khl[0][(s + 1) * 136 + dk]) + bf2f(khl[1][(s + 1) * 136 + dk]));
            gK[dk * 32 + half * 16 + i] = pack2f(v0, v1);
        }
    }
    __syncthreads();   // all khl reads done; safe to clobber with wtmp
    float* wtmp = (float*)&khl[0][0];   // [64][132]
    if (tid >= 128) {
        int dk = tid - 128;
#pragma unroll
        for (int s = 0; s < 64; s++) wtmp[s * 132 + dk] = bb[s];
    }
    __syncthreads();
    {   // W[s][dk] store (row-major)
        int s = tid >> 2, seg = tid & 3;
        uint32* gW = (uint32*)(P_W + (size_t)ch * 8192);
#pragma unroll
        for (int i = 0; i < 16; i++) {
            float v0 = wtmp[s * 132 + seg * 32 + 2 * i];
            float v1 = wtmp[s * 132 + seg * 32 + 2 * i + 1];
            gW[s * 64 + seg * 16 + i] = pack2f(v0, v1);
        }
    }
    if (tid < 64) P_cs[(size_t)ch * 64 + tid] = csL[tid];
}

__global__ __launch_bounds__(256)
void dr_phase2(const float* __restrict__ cv,
               const bf16_t* __restrict__ P_W, const bf16_t* __restrict__ P_U1T,
               const bf16_t* __restrict__ P_KT, const bf16_t* __restrict__ P_D,
               const float* __restrict__ P_cs, bf16_t* __restrict__ o16)
{
    __shared__ unsigned short Z16[64 * 136];   // [v][dk], stride 136
    __shared__ unsigned short uT16[64 * 72];   // [v][s],  stride 72
    const int h = blockIdx.x >> 1, g = blockIdx.x & 1, vbase = g * 64;
    const int tid = threadIdx.x, w = tid >> 6, lane = tid & 63;
    const int quad = lane >> 4, tl = lane & 15;
    const int trow = 16 * w + tl;

    for (int i = tid; i < 64 * 136 / 2; i += 256) ((uint32*)Z16)[i] = 0;
    __syncthreads();

    f32x4 Zacc[8];
#pragma unroll
    for (int i = 0; i < 8; i++)
#pragma unroll
        for (int r = 0; r < 4; r++) Zacc[i][r] = 0.f;

    for (int c = 0; c < 32; c++) {
        const int ch = h * 32 + c;
        const bf16_t* pW = P_W   + (size_t)ch * 8192;
        const bf16_t* pU = P_U1T + (size_t)ch * 8192;
        const bf16_t* pK = P_KT  + (size_t)ch * 8192;
        const bf16_t* pD = P_D   + (size_t)ch * 4096;
        const float*  pcs = P_cs + (size_t)ch * 64;
        const int t0c = c * 64;

        // ---- uT = U1T - Z (.) W  ([v][s]) ----
        f32x4 au[4];
#pragma unroll
        for (int j = 0; j < 4; j++)
#pragma unroll
            for (int r = 0; r < 4; r++) au[j][r] = 0.f;
        short8 zf[4];
#pragma unroll
        for (int kk = 0; kk < 4; kk++)
            zf[kk] = *(const short8*)&Z16[trow * 136 + 32 * kk + 8 * quad];
#pragma unroll
        for (int tj = 0; tj < 4; tj++)
#pragma unroll
            for (int kk = 0; kk < 4; kk++) {
                short8 wf = *(const short8*)&pW[(size_t)(16 * tj + tl) * 128 + 32 * kk + 8 * quad];
                au[tj] = __builtin_amdgcn_mfma_f32_16x16x32_bf16(zf[kk], wf, au[tj], 0, 0, 0);
            }
#pragma unroll
        for (int tj = 0; tj < 4; tj++)
#pragma unroll
            for (int r = 0; r < 4; r++) {
                int v = 16 * w + 4 * quad + r, s = 16 * tj + tl;
                float u1 = bf2f(pU[(size_t)(vbase + v) * 64 + s]);
                uT16[v * 72 + s] = f2bf(u1 - au[tj][r]);
            }
        __syncthreads();

        // ---- o = Qt (.) Z + D (.) uT  ([t][v]) ----
        f32x4 ao[4];
#pragma unroll
        for (int j = 0; j < 4; j++)
#pragma unroll
            for (int r = 0; r < 4; r++) ao[j][r] = 0.f;
        float qsc = __expf(pcs[trow]);
#pragma unroll
        for (int kk = 0; kk < 4; kk++) {
            const float* qp = cv + (size_t)(t0c + trow) * CDIM + h * HD + 32 * kk + 8 * quad;
            float4 qa = *(const float4*)qp;
            float4 qb = *(const float4*)(qp + 4);
            short8 qf;
            qf[0] = (short)f2bf(qa.x * qsc); qf[1] = (short)f2bf(qa.y * qsc);
            qf[2] = (short)f2bf(qa.z * qsc); qf[3] = (short)f2bf(qa.w * qsc);
            qf[4] = (short)f2bf(qb.x * qsc); qf[5] = (short)f2bf(qb.y * qsc);
            qf[6] = (short)f2bf(qb.z * qsc); qf[7] = (short)f2bf(qb.w * qsc);
#pragma unroll
            for (int tj = 0; tj < 4; tj++) {
                short8 zb = *(const short8*)&Z16[(16 * tj + tl) * 136 + 32 * kk + 8 * quad];
                ao[tj] = __builtin_amdgcn_mfma_f32_16x16x32_bf16(qf, zb, ao[tj], 0, 0, 0);
            }
        }
#pragma unroll
        for (int k2 = 0; k2 < 2; k2++) {
            short8 df = *(const short8*)&pD[(size_t)trow * 64 + 32 * k2 + 8 * quad];
#pragma unroll
            for (int tj = 0; tj < 4; tj++) {
                short8 ub = *(const short8*)&uT16[(16 * tj + tl) * 72 + 32 * k2 + 8 * quad];
                ao[tj] = __builtin_amdgcn_mfma_f32_16x16x32_bf16(df, ub, ao[tj], 0, 0, 0);
            }
        }
#pragma unroll
        for (int tj = 0; tj < 4; tj++)
#pragma unroll
            for (int r = 0; r < 4; r++) {
                int t = 16 * w + 4 * quad + r, v = 16 * tj + tl;
                o16[(size_t)(t0c + t) * DM + h * HD + vbase + v] = f2bf(ao[tj][r]);
            }
        __syncthreads();   // all Z16/uT16 reads done

        // ---- Z = aL*Z + uT (.) KhatT  ([v][dk]) ----
        float aL = __expf(pcs[63]);
#pragma unroll
        for (int td = 0; td < 8; td++)
#pragma unroll
            for (int r = 0; r < 4; r++) Zacc[td][r] *= aL;
#pragma unroll
        for (int k2 = 0; k2 < 2; k2++) {
            short8 uf = *(const short8*)&uT16[trow * 72 + 32 * k2 + 8 * quad];
#pragma unroll
            for (int td = 0; td < 8; td++) {
                short8 kf = *(const short8*)&pK[(size_t)(16 * td + tl) * 64 + 32 * k2 + 8 * quad];
                Zacc[td] = __builtin_amdgcn_mfma_f32_16x16x32_bf16(uf, kf, Zacc[td], 0, 0, 0);
            }
        }
#pragma unroll
        for (int td = 0; td < 8; td++)
#pragma unroll
            for (int r = 0; r < 4; r++) {
                int v = 16 * w + 4 * quad + r, dk = 16 * td + tl;
                Z16[v * 136 + dk] = f2bf(Zacc[td][r]);
            }
        __syncthreads();
    }
}

// ---------------------------------------------------------------------------
// Workspace layout (float offsets), 116.65 MB total (identical to R2 proven):
//   cv    [0, 12582912)                    (x16 bf16 overlays head, dead early)
//   u16   [12582912, 18874368)  bf16, dead after convgen ->
//         P_W [12582912,+2097152) P_U1T [14680064,+2097152) P_KT [16777216,+2097152)
//   h116  [18874368, 19660800)  dead after convgen
//   decT  [19660800,+32768)  betaT [19693568,+32768)
//   wT    [19726336, +9437184=29163520): W_qkvT/gw1T/gw2T sequentially; after
//         convgen: P_D [19726336,+1048576) P_cs [20774912,+32768)
//         WoT [20807680,+2097152) o16 [22904832,+2097152)
// ---------------------------------------------------------------------------
extern "C" void kernel_launch(void* const* d_in, const int* in_sizes, int n_in,
                              void* d_out, int out_size, void* d_ws, size_t ws_size,
                              hipStream_t stream)
{
    const float* x      = (const float*)d_in[0];
    const float* W_qkv  = (const float*)d_in[1];
    const float* W_ba   = (const float*)d_in[2];
    const float* gen_w1 = (const float*)d_in[3];
    const float* gen_w2 = (const float*)d_in[4];
    const float* gen_b2 = (const float*)d_in[5];
    const float* W_o    = (const float*)d_in[6];
    float* y  = (float*)d_out;
    float* wsf = (float*)d_ws;

    float*  cv    = wsf;
    bf16_t* x16   = (bf16_t*)wsf;
    bf16_t* u16   = (bf16_t*)(wsf + 12582912);
    bf16_t* h116  = (bf16_t*)(wsf + 18874368);
    float*  decT  = wsf + 19660800;
    float*  betaT = wsf + 19693568;
    bf16_t* wT    = (bf16_t*)(wsf + 19726336);
    bf16_t* P_W   = (bf16_t*)(wsf + 12582912);
    bf16_t* P_U1T = (bf16_t*)(wsf + 14680064);
    bf16_t* P_KT  = (bf16_t*)(wsf + 16777216);
    bf16_t* P_D   = (bf16_t*)(wsf + 19726336);
    float*  P_cs  = wsf + 20774912;
    bf16_t* WoT   = (bf16_t*)(wsf + 20807680);
    bf16_t* o16   = (bf16_t*)(wsf + 22904832);

    dim3 blk(256);

    tcast<<<dim3(192, 64), blk, 0, stream>>>(W_qkv, wT, DM, CDIM);
    castk<<<dim3(4096), blk, 0, stream>>>(x, x16, (T_LEN * DM) / 4);
    mgemm<1, 6><<<dim3(768), blk, 0, stream>>>(x16, wT, nullptr, u16, T_LEN, CDIM, DM);
    ba_kernel<<<dim3(256), blk, 0, stream>>>(x, W_ba, betaT, decT);
    tcast<<<dim3(24, 192), blk, 0, stream>>>(gen_w1, wT, CDIM, GH);
    mgemm<2, 0><<<dim3(6, 16), blk, 0, stream>>>(u16, wT, nullptr, h116, T_LEN, GH, CDIM);
    tcast<<<dim3(768, 24), blk, 0, stream>>>(gen_w2, wT, GH, NOUT);
    convgen<<<dim3(3072), blk, 0, stream>>>(h116, wT, gen_b2, u16, cv);
    norm_qk<<<dim3(16384), blk, 0, stream>>>(cv);
    dr_phase1<<<dim3(512), blk, 0, stream>>>(cv, decT, betaT, P_W, P_U1T, P_KT, P_D, P_cs);
    tcast<<<dim3(64, 64), blk, 0, stream>>>(W_o, WoT, DM, DM);
    dr_phase2<<<dim3(32), blk, 0, stream>>>(cv, P_W, P_U1T, P_KT, P_D, P_cs, o16);
    mgemm<0, 2><<<dim3(256), blk, 0, stream>>>(o16, WoT, y, nullptr, T_LEN, DM, DM);
}

// Round 5
// 1094.090 us; speedup vs baseline: 4.0292x; 1.0590x over previous
//
#include <hip/hip_runtime.h>
#include <math.h>

#define T_LEN 2048
#define DM    2048
#define NH    16
#define HD    128
#define CDIM  6144
#define GH    768
#define NOUT  24576

typedef unsigned short bf16_t;
typedef unsigned int   uint32;
typedef __attribute__((ext_vector_type(8))) short short8;
typedef __attribute__((ext_vector_type(4))) float f32x4;

__device__ __forceinline__ float silu_f(float v) { return v / (1.f + __expf(-v)); }

__device__ __forceinline__ bf16_t f2bf(float f) {
    uint32 u = __float_as_uint(f);
    u = (u + 0x7fff + ((u >> 16) & 1)) >> 16;   // RNE
    return (bf16_t)u;
}
__device__ __forceinline__ float bf2f(bf16_t b) {
    return __uint_as_float(((uint32)b) << 16);
}
__device__ __forceinline__ uint32 pack2f(float a, float b) {
    return (uint32)f2bf(a) | ((uint32)f2bf(b) << 16);
}

// async global->LDS, 16B per lane; LDS dest = wave-uniform base + lane*16
#define GLL(gptr, lptr) \
  __builtin_amdgcn_global_load_lds((const __attribute__((address_space(1))) void*)(gptr), \
                                   (__attribute__((address_space(3))) void*)(lptr), 16, 0, 0)

// ---------------------------------------------------------------------------
// Transpose + cast: W [K][N] fp32 -> Wt [N][K] bf16
// ---------------------------------------------------------------------------
__global__ __launch_bounds__(256)
void tcast(const float* __restrict__ W, bf16_t* __restrict__ Wt, int K, int N)
{
    __shared__ float tile[32][33];
    const int n0 = blockIdx.x * 32, k0 = blockIdx.y * 32;
    const int c = threadIdx.x & 31, r = threadIdx.x >> 5;
#pragma unroll
    for (int i = 0; i < 4; i++)
        tile[r + i * 8][c] = W[(size_t)(k0 + r + i * 8) * N + n0 + c];
    __syncthreads();
#pragma unroll
    for (int i = 0; i < 4; i++)
        Wt[(size_t)(n0 + r + i * 8) * K + k0 + c] = f2bf(tile[c][r + i * 8]);
}

// elementwise fp32 -> bf16 (4 per thread)
__global__ __launch_bounds__(256)
void castk(const float* __restrict__ in, bf16_t* __restrict__ out, int n4)
{
    int i = blockIdx.x * 256 + threadIdx.x;
    if (i >= n4) return;
    float4 v = ((const float4*)in)[i];
    uint2 p;
    p.x = pack2f(v.x, v.y);
    p.y = pack2f(v.z, v.w);
    ((uint2*)out)[i] = p;
}

// ---------------------------------------------------------------------------
// bf16 MFMA GEMM (m97 structure): C[M,N] = A[M,K] @ Bt[N,K]^T
// ---------------------------------------------------------------------------
template<int EPI, int NPER>
__global__ __launch_bounds__(256)
void mgemm(const bf16_t* __restrict__ A, const bf16_t* __restrict__ Bt,
           float* __restrict__ C, bf16_t* __restrict__ C16,
           int M, int N, int K)
{
    __shared__ bf16_t As[4096];
    __shared__ bf16_t Bs[4096];
    const int tid = threadIdx.x;
    const int lane = tid & 63, w = tid >> 6;
    const int quad = lane >> 4, tl = lane & 15;
    int bm0, bn0;
    if (NPER == 0) { bm0 = blockIdx.y * 128; bn0 = blockIdx.x * 128; }
    else {
        int bx = blockIdx.x, xcd = bx & 7, seq = bx >> 3;
        bm0 = (seq & 15) * 128;
        bn0 = (xcd * NPER + (seq >> 4)) * 128;
    }
    const int wm = (w >> 1) * 64, wn = (w & 1) * 64;

    const bf16_t* a0 = A  + (size_t)(bm0 + (tid & 127)) * K + ((tid >> 7) << 3);
    const bf16_t* b0 = Bt + (size_t)(bn0 + (tid & 127)) * K + ((tid >> 7) << 3);
    bf16_t* asd0 = &As[w * 512];
    bf16_t* asd1 = &As[2048 + w * 512];
    bf16_t* bsd0 = &Bs[w * 512];
    bf16_t* bsd1 = &Bs[2048 + w * 512];

    f32x4 acc[4][4];
#pragma unroll
    for (int i = 0; i < 4; i++)
#pragma unroll
        for (int j = 0; j < 4; j++) { acc[i][j][0] = 0.f; acc[i][j][1] = 0.f; acc[i][j][2] = 0.f; acc[i][j][3] = 0.f; }

    for (int k0 = 0; k0 < K; k0 += 32) {
        __syncthreads();
        GLL(a0 + k0,      asd0);
        GLL(a0 + k0 + 16, asd1);
        GLL(b0 + k0,      bsd0);
        GLL(b0 + k0 + 16, bsd1);
        __syncthreads();
        short8 af[4], bfr[4];
#pragma unroll
        for (int mt = 0; mt < 4; mt++)
            af[mt] = *(const short8*)&As[(quad * 128 + wm + mt * 16 + tl) * 8];
#pragma unroll
        for (int nt = 0; nt < 4; nt++)
            bfr[nt] = *(const short8*)&Bs[(quad * 128 + wn + nt * 16 + tl) * 8];
#pragma unroll
        for (int mt = 0; mt < 4; mt++)
#pragma unroll
            for (int nt = 0; nt < 4; nt++)
                acc[mt][nt] = __builtin_amdgcn_mfma_f32_16x16x32_bf16(af[mt], bfr[nt], acc[mt][nt], 0, 0, 0);
    }

#pragma unroll
    for (int mt = 0; mt < 4; mt++) {
        int rbase = bm0 + wm + mt * 16 + quad * 4;
#pragma unroll
        for (int nt = 0; nt < 4; nt++) {
            int cg = bn0 + wn + nt * 16 + tl;
#pragma unroll
            for (int r = 0; r < 4; r++) {
                float v = acc[mt][nt][r];
                size_t idx = (size_t)(rbase + r) * N + cg;
                if (EPI == 0)      C[idx]   = v;
                else if (EPI == 1) C16[idx] = f2bf(v);
                else               C16[idx] = f2bf(silu_f(v));
            }
        }
    }
}

// ---------------------------------------------------------------------------
// convgen: kern = h1 @ gen_w2 + b2 (MFMA), fused causal W=4 conv + silu.
// Epilogue: u halo tile staged in LDS (coalesced), conv accumulated into a
// padded LDS tile, then fully-coalesced fp32 stores (no write amplification).
// ---------------------------------------------------------------------------
__global__ __launch_bounds__(256)
void convgen(const bf16_t* __restrict__ A, const bf16_t* __restrict__ Bt,
             const float* __restrict__ b2, const bf16_t* __restrict__ u16c,
             float* __restrict__ cvout)
{
    const int K = GH;
    __shared__ __align__(16) char smraw[36864];
    bf16_t* As = (bf16_t*)smraw;
    bf16_t* Bs = As + 4096;
    float* uf   = (float*)smraw;              // [131][36]  (epilogue, overlays As/Bs)
    float* outs = (float*)(smraw + 18880);    // [128][33]

    const int tid = threadIdx.x;
    const int lane = tid & 63, w = tid >> 6;
    const int quad = lane >> 4, tl = lane & 15;
    const int bx = blockIdx.x, xcd = bx & 7, seq = bx >> 3;
    const int bm0 = (seq & 15) * 128;
    const int bn0 = (xcd * 24 + (seq >> 4)) * 128;
    const int wm = (w >> 1) * 64, wn = (w & 1) * 64;

    const bf16_t* a0 = A  + (size_t)(bm0 + (tid & 127)) * K + ((tid >> 7) << 3);
    const bf16_t* b0 = Bt + (size_t)(bn0 + (tid & 127)) * K + ((tid >> 7) << 3);
    bf16_t* asd0 = &As[w * 512];
    bf16_t* asd1 = &As[2048 + w * 512];
    bf16_t* bsd0 = &Bs[w * 512];
    bf16_t* bsd1 = &Bs[2048 + w * 512];

    f32x4 acc[4][4];
#pragma unroll
    for (int i = 0; i < 4; i++)
#pragma unroll
        for (int j = 0; j < 4; j++) { acc[i][j][0] = 0.f; acc[i][j][1] = 0.f; acc[i][j][2] = 0.f; acc[i][j][3] = 0.f; }

    for (int k0 = 0; k0 < K; k0 += 32) {
        __syncthreads();
        GLL(a0 + k0,      asd0);
        GLL(a0 + k0 + 16, asd1);
        GLL(b0 + k0,      bsd0);
        GLL(b0 + k0 + 16, bsd1);
        __syncthreads();
        short8 af[4], bfr[4];
#pragma unroll
        for (int mt = 0; mt < 4; mt++)
            af[mt] = *(const short8*)&As[(quad * 128 + wm + mt * 16 + tl) * 8];
#pragma unroll
        for (int nt = 0; nt < 4; nt++)
            bfr[nt] = *(const short8*)&Bs[(quad * 128 + wn + nt * 16 + tl) * 8];
#pragma unroll
        for (int mt = 0; mt < 4; mt++)
#pragma unroll
            for (int nt = 0; nt < 4; nt++)
                acc[mt][nt] = __builtin_amdgcn_mfma_f32_16x16x32_bf16(af[mt], bfr[nt], acc[mt][nt], 0, 0, 0);
    }
    __syncthreads();   // fragments consumed; safe to overlay As/Bs with uf/outs

    const int d0 = bn0 >> 2;
    // stage u halo tile: rows t = bm0-3 .. bm0+127, 32 d-columns, fp32 in LDS
    for (int i = tid; i < 131 * 8; i += 256) {
        int row = i >> 3, seg = i & 7;
        int t = bm0 - 3 + row;
        float* dst = &uf[row * 36 + seg * 4];
        if (t >= 0) {
            uint2 p = *(const uint2*)&u16c[(size_t)t * CDIM + d0 + seg * 4];
            dst[0] = bf2f((bf16_t)(p.x & 0xffff));
            dst[1] = bf2f((bf16_t)(p.x >> 16));
            dst[2] = bf2f((bf16_t)(p.y & 0xffff));
            dst[3] = bf2f((bf16_t)(p.y >> 16));
        } else {
            dst[0] = 0.f; dst[1] = 0.f; dst[2] = 0.f; dst[3] = 0.f;
        }
    }
    __syncthreads();

    const int wi = tl & 3;
#pragma unroll
    for (int nt = 0; nt < 4; nt++) {
        int n = bn0 + wn + nt * 16 + tl;
        float b2v = b2[n];
        int dloc = (wn >> 2) + nt * 4 + (tl >> 2);
#pragma unroll
        for (int mt = 0; mt < 4; mt++) {
            int trl = wm + mt * 16 + quad * 4;
#pragma unroll
            for (int r = 0; r < 4; r++) {
                float p = (acc[mt][nt][r] + b2v) * uf[(trl + r + wi) * 36 + dloc];
                p += __shfl_xor(p, 1);
                p += __shfl_xor(p, 2);
                if (wi == 0) outs[(trl + r) * 33 + dloc] = p;
            }
        }
    }
    __syncthreads();

    for (int i = tid; i < 4096; i += 256) {
        int row = i >> 5, col = i & 31;
        cvout[(size_t)(bm0 + row) * CDIM + d0 + col] = silu_f(outs[row * 33 + col]);
    }
}

// ---------------------------------------------------------------------------
// ba: beta=sigmoid(b), decay=sigmoid(-a); outputs transposed [H][T]
// ---------------------------------------------------------------------------
__global__ __launch_bounds__(256)
void ba_kernel(const float* __restrict__ x, const float* __restrict__ Wba,
               float* __restrict__ betaT, float* __restrict__ decT)
{
    const int t = blockIdx.x * 8 + (threadIdx.x >> 5);
    const int c = threadIdx.x & 31;
    const float* xr = x + (size_t)t * DM;
    float acc = 0.f;
#pragma unroll 4
    for (int k0 = 0; k0 < DM; k0 += 4) {
        float4 xv = *(const float4*)&xr[k0];
        acc = fmaf(xv.x, Wba[(k0 + 0) * 32 + c], acc);
        acc = fmaf(xv.y, Wba[(k0 + 1) * 32 + c], acc);
        acc = fmaf(xv.z, Wba[(k0 + 2) * 32 + c], acc);
        acc = fmaf(xv.w, Wba[(k0 + 3) * 32 + c], acc);
    }
    float val = 1.f / (1.f + __expf((c < 16) ? -acc : acc));
    if (c < 16) betaT[(size_t)c * T_LEN + t] = val;
    else        decT[(size_t)(c - 16) * T_LEN + t] = val;
}

// ===========================================================================
// Chunked gated delta rule (UT transform), L = 64.  Phase 1 now also performs
// the q/k l2norm (norm_qk kernel removed) and emits Qn = e^{c_t} qhat (bf16)
// for phase 2.
// ===========================================================================
__global__ __launch_bounds__(256)
void dr_phase1(const float* __restrict__ cv, const float* __restrict__ decT,
               const float* __restrict__ betaT,
               bf16_t* __restrict__ P_W, bf16_t* __restrict__ P_U1T,
               bf16_t* __restrict__ P_KT, bf16_t* __restrict__ P_D,
               float* __restrict__ P_cs, bf16_t* __restrict__ Qn)
{
    __shared__ float kfn[64 * 132];     // normalized k, fp32 (33.8 KB)
    __shared__ float A_ls[64 * 68];     // A[s][r] (17.4 KB)
    __shared__ float csL[64], betaL[64], eaL[64], ebL[64], rnk[64];

    const int ch = blockIdx.x, h = ch >> 5, c = ch & 31;
    const int t0 = c * 64;
    const int tid = threadIdx.x, w = tid >> 6, lane = tid & 63;
    const int quad = lane >> 4, tl = lane & 15;

    const float* kg = cv + (size_t)t0 * CDIM + NH * HD + h * HD;
    const float* qg = cv + (size_t)t0 * CDIM + h * HD;
    const float* vg = cv + (size_t)t0 * CDIM + 2 * NH * HD + h * HD;

    // --- stage raw k into LDS (fp32) ---
#pragma unroll
    for (int i = 0; i < 8; i++) {
        int idx = tid + 256 * i;
        int t = idx >> 5, c4 = (idx & 31) * 4;
        *(float4*)&kfn[t * 132 + c4] = *(const float4*)&kg[(size_t)t * CDIM + c4];
    }
    // --- cumulative log decay, beta, exp tables (wave 0 lanes) ---
    if (tid < 64) {
        float dec = decT[(size_t)h * T_LEN + t0 + tid];
        float csum = __logf(dec);
#pragma unroll
        for (int off = 1; off < 64; off <<= 1) {
            float o = __shfl_up(csum, off);
            if (tid >= off) csum += o;
        }
        csL[tid]   = csum;
        eaL[tid]   = __expf(csum);
        betaL[tid] = betaT[(size_t)h * T_LEN + t0 + tid];
        float c63 = __shfl(csum, 63);
        ebL[tid]  = __expf(c63 - csum);
    }
    __syncthreads();

    // --- k row norms (4 threads/row) ---
    {
        int t = tid >> 2, p = tid & 3;
        float ss = 0.f;
#pragma unroll
        for (int j = 0; j < 8; j++) {
            float4 v = *(const float4*)&kfn[t * 132 + p * 32 + j * 4];
            ss += v.x * v.x + v.y * v.y + v.z * v.z + v.w * v.w;
        }
        ss += __shfl_xor(ss, 1);
        ss += __shfl_xor(ss, 2);
        if (p == 0) rnk[t] = rsqrtf(ss + 1e-6f);
    }
    __syncthreads();
    // --- normalize k in LDS ---
#pragma unroll
    for (int i = 0; i < 8; i++) {
        int idx = tid + 256 * i;
        int t = idx >> 5, c4 = (idx & 31) * 4;
        float4 v = *(float4*)&kfn[t * 132 + c4];
        float rs = rnk[t];
        v.x *= rs; v.y *= rs; v.z *= rs; v.w *= rs;
        *(float4*)&kfn[t * 132 + c4] = v;
    }
    __syncthreads();

    // --- q: load row, normalize in regs (quad shuffles), emit frags + Qn ---
    const int row = 16 * w + tl;
    float qv[4][8];
    float ssq = 0.f;
#pragma unroll
    for (int kk = 0; kk < 4; kk++) {
        const float* qp = &qg[(size_t)row * CDIM + 32 * kk + 8 * quad];
        *(float4*)&qv[kk][0] = *(const float4*)qp;
        *(float4*)&qv[kk][4] = *(const float4*)(qp + 4);
#pragma unroll
        for (int j = 0; j < 8; j++) ssq += qv[kk][j] * qv[kk][j];
    }
    ssq += __shfl_xor(ssq, 16);
    ssq += __shfl_xor(ssq, 32);
    const float qsc = rsqrtf(ssq + 1e-6f) * 0.08838834764831845f;   // * DK^-0.5
    const float qe  = qsc * eaL[row];                                // fold e^{c_t}

    short8 xqh[4], xql[4], xkh[4], xkl[4];
    {
        bf16_t* Qrow = Qn + ((size_t)(h * T_LEN + t0 + row)) * 128;
#pragma unroll
        for (int kk = 0; kk < 4; kk++) {
            short8 qn8;
#pragma unroll
            for (int j = 0; j < 8; j++) {
                float qx = qv[kk][j] * qsc;
                bf16_t hh = f2bf(qx);
                xqh[kk][j] = (short)hh;
                xql[kk][j] = (short)f2bf(qx - bf2f(hh));
                qn8[j] = (short)f2bf(qv[kk][j] * qe);
            }
            *(short8*)&Qrow[32 * kk + 8 * quad] = qn8;
        }
#pragma unroll
        for (int kk = 0; kk < 4; kk++) {
            float kv[8];
            *(float4*)&kv[0] = *(const float4*)&kfn[row * 132 + 32 * kk + 8 * quad];
            *(float4*)&kv[4] = *(const float4*)&kfn[row * 132 + 32 * kk + 8 * quad + 4];
#pragma unroll
            for (int j = 0; j < 8; j++) {
                bf16_t hh = f2bf(kv[j]);
                xkh[kk][j] = (short)hh;
                xkl[kk][j] = (short)f2bf(kv[j] - bf2f(hh));
            }
        }
    }

    // --- KK^T and QK^T (split-bf16, 2-term; B operand split on the fly) ---
    f32x4 aK[4], aQ[4];
#pragma unroll
    for (int j = 0; j < 4; j++)
#pragma unroll
        for (int r = 0; r < 4; r++) { aK[j][r] = 0.f; aQ[j][r] = 0.f; }
#pragma unroll
    for (int tj = 0; tj < 4; tj++) {
#pragma unroll
        for (int kk = 0; kk < 4; kk++) {
            float yv[8];
            int yoff = (16 * tj + tl) * 132 + 32 * kk + 8 * quad;
            *(float4*)&yv[0] = *(const float4*)&kfn[yoff];
            *(float4*)&yv[4] = *(const float4*)&kfn[yoff + 4];
            short8 yh, yl;
#pragma unroll
            for (int j = 0; j < 8; j++) {
                bf16_t hh = f2bf(yv[j]);
                yh[j] = (short)hh;
                yl[j] = (short)f2bf(yv[j] - bf2f(hh));
            }
            aK[tj] = __builtin_amdgcn_mfma_f32_16x16x32_bf16(xkh[kk], yh, aK[tj], 0, 0, 0);
            aK[tj] = __builtin_amdgcn_mfma_f32_16x16x32_bf16(xkh[kk], yl, aK[tj], 0, 0, 0);
            aK[tj] = __builtin_amdgcn_mfma_f32_16x16x32_bf16(xkl[kk], yh, aK[tj], 0, 0, 0);
            aQ[tj] = __builtin_amdgcn_mfma_f32_16x16x32_bf16(xqh[kk], yh, aQ[tj], 0, 0, 0);
            aQ[tj] = __builtin_amdgcn_mfma_f32_16x16x32_bf16(xqh[kk], yl, aQ[tj], 0, 0, 0);
            aQ[tj] = __builtin_amdgcn_mfma_f32_16x16x32_bf16(xql[kk], yh, aQ[tj], 0, 0, 0);
        }
    }
    // --- epilogue: A (LDS, fp32) and D (global, bf16) ---
    {
        bf16_t* gD = P_D + (size_t)ch * 4096;
#pragma unroll
        for (int tj = 0; tj < 4; tj++) {
#pragma unroll
            for (int r = 0; r < 4; r++) {
                int s  = 16 * w + 4 * quad + r;
                int rr = 16 * tj + tl;
                float e = __expf(csL[s] - csL[rr]);
                A_ls[s * 68 + rr] = (s > rr) ? betaL[s] * e * aK[tj][r] : 0.f;
                gD[s * 64 + rr] = (s >= rr) ? f2bf(e * aQ[tj][r]) : (bf16_t)0;
            }
        }
    }
    __syncthreads();

    // --- forward substitution: (I+A) u = b, 256 RHS columns ---
    float bb[64];
    if (tid < 128) {
        int j = tid;
#pragma unroll
        for (int s = 0; s < 64; s++) bb[s] = betaL[s] * vg[(size_t)s * CDIM + j];
    } else {
        int dk = tid - 128;
#pragma unroll
        for (int s = 0; s < 64; s++)
            bb[s] = betaL[s] * eaL[s] * kfn[s * 132 + dk];
    }
#pragma unroll
    for (int r4 = 0; r4 < 64; r4 += 4) {
        float u0 = bb[r4];
        float u1 = bb[r4 + 1] - A_ls[(r4 + 1) * 68 + r4] * u0;
        float u2 = bb[r4 + 2] - A_ls[(r4 + 2) * 68 + r4] * u0 - A_ls[(r4 + 2) * 68 + r4 + 1] * u1;
        float u3 = bb[r4 + 3] - A_ls[(r4 + 3) * 68 + r4] * u0 - A_ls[(r4 + 3) * 68 + r4 + 1] * u1
                              - A_ls[(r4 + 3) * 68 + r4 + 2] * u2;
        bb[r4] = u0; bb[r4 + 1] = u1; bb[r4 + 2] = u2; bb[r4 + 3] = u3;
#pragma unroll
        for (int s = r4 + 4; s < 64; s++) {
            float4 a4 = *(const float4*)&A_ls[s * 68 + r4];
            bb[s] -= a4.x * u0 + a4.y * u1 + a4.z * u2 + a4.w * u3;
        }
    }
    // --- stores ---
    if (tid < 128) {   // U1T row j (contiguous 64)
        uint32* gU = (uint32*)(P_U1T + (size_t)ch * 8192) + tid * 32;
#pragma unroll
        for (int i = 0; i < 32; i++) gU[i] = pack2f(bb[2 * i], bb[2 * i + 1]);
    }
    {   // KhatT[dk][s] = e^{c63-cs} khat_s[dk]
        int dk = tid >> 1, half = tid & 1;
        uint32* gK = (uint32*)(P_KT + (size_t)ch * 8192);
#pragma unroll
        for (int i = 0; i < 16; i++) {
            int s = half * 32 + 2 * i;
            float v0 = ebL[s]     * kfn[s * 132 + dk];
            float v1 = ebL[s + 1] * kfn[(s + 1) * 132 + dk];
            gK[dk * 32 + half * 16 + i] = pack2f(v0, v1);
        }
    }
    __syncthreads();   // all kfn reads done; safe to clobber with wtmp
    float* wtmp = kfn;   // [64][132]
    if (tid >= 128) {
        int dk = tid - 128;
#pragma unroll
        for (int s = 0; s < 64; s++) wtmp[s * 132 + dk] = bb[s];
    }
    __syncthreads();
    {   // W[s][dk] store (row-major)
        int s = tid >> 2, seg = tid & 3;
        uint32* gW = (uint32*)(P_W + (size_t)ch * 8192);
#pragma unroll
        for (int i = 0; i < 16; i++) {
            float v0 = wtmp[s * 132 + seg * 32 + 2 * i];
            float v1 = wtmp[s * 132 + seg * 32 + 2 * i + 1];
            gW[s * 64 + seg * 16 + i] = pack2f(v0, v1);
        }
    }
    if (tid < 64) P_cs[(size_t)ch * 64 + tid] = csL[tid];
}

__global__ __launch_bounds__(256)
void dr_phase2(const bf16_t* __restrict__ Qn,
               const bf16_t* __restrict__ P_W, const bf16_t* __restrict__ P_U1T,
               const bf16_t* __restrict__ P_KT, const bf16_t* __restrict__ P_D,
               const float* __restrict__ P_cs, bf16_t* __restrict__ o16)
{
    __shared__ unsigned short Z16[64 * 136];   // [v][dk], stride 136
    __shared__ unsigned short uT16[64 * 72];   // [v][s],  stride 72
    const int h = blockIdx.x >> 1, g = blockIdx.x & 1, vbase = g * 64;
    const int tid = threadIdx.x, w = tid >> 6, lane = tid & 63;
    const int quad = lane >> 4, tl = lane & 15;
    const int trow = 16 * w + tl;

    for (int i = tid; i < 64 * 136 / 2; i += 256) ((uint32*)Z16)[i] = 0;
    __syncthreads();

    f32x4 Zacc[8];
#pragma unroll
    for (int i = 0; i < 8; i++)
#pragma unroll
        for (int r = 0; r < 4; r++) Zacc[i][r] = 0.f;

    for (int c = 0; c < 32; c++) {
        const int ch = h * 32 + c;
        const bf16_t* pW = P_W   + (size_t)ch * 8192;
        const bf16_t* pU = P_U1T + (size_t)ch * 8192;
        const bf16_t* pK = P_KT  + (size_t)ch * 8192;
        const bf16_t* pD = P_D   + (size_t)ch * 4096;
        const float*  pcs = P_cs + (size_t)ch * 64;
        const int t0c = c * 64;

        // ---- uT = U1T - Z (.) W  ([v][s]) ----
        f32x4 au[4];
#pragma unroll
        for (int j = 0; j < 4; j++)
#pragma unroll
            for (int r = 0; r < 4; r++) au[j][r] = 0.f;
        short8 zf[4];
#pragma unroll
        for (int kk = 0; kk < 4; kk++)
            zf[kk] = *(const short8*)&Z16[trow * 136 + 32 * kk + 8 * quad];
#pragma unroll
        for (int tj = 0; tj < 4; tj++)
#pragma unroll
            for (int kk = 0; kk < 4; kk++) {
                short8 wf = *(const short8*)&pW[(size_t)(16 * tj + tl) * 128 + 32 * kk + 8 * quad];
                au[tj] = __builtin_amdgcn_mfma_f32_16x16x32_bf16(zf[kk], wf, au[tj], 0, 0, 0);
            }
#pragma unroll
        for (int tj = 0; tj < 4; tj++)
#pragma unroll
            for (int r = 0; r < 4; r++) {
                int v = 16 * w + 4 * quad + r, s = 16 * tj + tl;
                float u1 = bf2f(pU[(size_t)(vbase + v) * 64 + s]);
                uT16[v * 72 + s] = f2bf(u1 - au[tj][r]);
            }
        __syncthreads();

        // ---- o = Qn (.) Z + D (.) uT  ([t][v]) ----
        f32x4 ao[4];
#pragma unroll
        for (int j = 0; j < 4; j++)
#pragma unroll
            for (int r = 0; r < 4; r++) ao[j][r] = 0.f;
        const bf16_t* pQ = Qn + ((size_t)(h * T_LEN + t0c + trow)) * 128;
#pragma unroll
        for (int kk = 0; kk < 4; kk++) {
            short8 qf = *(const short8*)&pQ[32 * kk + 8 * quad];
#pragma unroll
            for (int tj = 0; tj < 4; tj++) {
                short8 zb = *(const short8*)&Z16[(16 * tj + tl) * 136 + 32 * kk + 8 * quad];
                ao[tj] = __builtin_amdgcn_mfma_f32_16x16x32_bf16(qf, zb, ao[tj], 0, 0, 0);
            }
        }
#pragma unroll
        for (int k2 = 0; k2 < 2; k2++) {
            short8 df = *(const short8*)&pD[(size_t)trow * 64 + 32 * k2 + 8 * quad];
#pragma unroll
            for (int tj = 0; tj < 4; tj++) {
                short8 ub = *(const short8*)&uT16[(16 * tj + tl) * 72 + 32 * k2 + 8 * quad];
                ao[tj] = __builtin_amdgcn_mfma_f32_16x16x32_bf16(df, ub, ao[tj], 0, 0, 0);
            }
        }
#pragma unroll
        for (int tj = 0; tj < 4; tj++)
#pragma unroll
            for (int r = 0; r < 4; r++) {
                int t = 16 * w + 4 * quad + r, v = 16 * tj + tl;
                o16[(size_t)(t0c + t) * DM + h * HD + vbase + v] = f2bf(ao[tj][r]);
            }
        __syncthreads();   // all Z16/uT16 reads done

        // ---- Z = aL*Z + uT (.) KhatT  ([v][dk]) ----
        float aL = __expf(pcs[63]);
#pragma unroll
        for (int td = 0; td < 8; td++)
#pragma unroll
            for (int r = 0; r < 4; r++) Zacc[td][r] *= aL;
#pragma unroll
        for (int k2 = 0; k2 < 2; k2++) {
            short8 uf = *(const short8*)&uT16[trow * 72 + 32 * k2 + 8 * quad];
#pragma unroll
            for (int td = 0; td < 8; td++) {
                short8 kf = *(const short8*)&pK[(size_t)(16 * td + tl) * 64 + 32 * k2 + 8 * quad];
                Zacc[td] = __builtin_amdgcn_mfma_f32_16x16x32_bf16(uf, kf, Zacc[td], 0, 0, 0);
            }
        }
#pragma unroll
        for (int td = 0; td < 8; td++)
#pragma unroll
            for (int r = 0; r < 4; r++) {
                int v = 16 * w + 4 * quad + r, dk = 16 * td + tl;
                Z16[v * 136 + dk] = f2bf(Zacc[td][r]);
            }
        __syncthreads();
    }
}

// ---------------------------------------------------------------------------
// Workspace layout (float offsets), 116.65 MB total (same proven footprint):
//   cv    [0, 12582912)
//   P_W [12582912,+2097152) P_U1T [14680064,+2097152) P_KT [16777216,+2097152)
//   h116  [18874368, 19660800)
//   decT  [19660800,+32768)  betaT [19693568,+32768)
//   wT    [19726336,+9437184=29163520): gw2T etc; after convgen:
//       P_D [19726336,+1048576) P_cs [20774912,+32768) WoT [20807680,+2097152)
//       o16 [22904832,+2097152)  Qn [25001984,+2097152)  (ends 27099136)
// ---------------------------------------------------------------------------
extern "C" void kernel_launch(void* const* d_in, const int* in_sizes, int n_in,
                              void* d_out, int out_size, void* d_ws, size_t ws_size,
                              hipStream_t stream)
{
    const float* x      = (const float*)d_in[0];
    const float* W_qkv  = (const float*)d_in[1];
    const float* W_ba   = (const float*)d_in[2];
    const float* gen_w1 = (const float*)d_in[3];
    const float* gen_w2 = (const float*)d_in[4];
    const float* gen_b2 = (const float*)d_in[5];
    const float* W_o    = (const float*)d_in[6];
    float* y  = (float*)d_out;
    float* wsf = (float*)d_ws;

    float*  cv    = wsf;
    bf16_t* x16   = (bf16_t*)wsf;
    bf16_t* u16   = (bf16_t*)(wsf + 12582912);
    bf16_t* h116  = (bf16_t*)(wsf + 18874368);
    float*  decT  = wsf + 19660800;
    float*  betaT = wsf + 19693568;
    bf16_t* wT    = (bf16_t*)(wsf + 19726336);
    bf16_t* P_W   = (bf16_t*)(wsf + 12582912);
    bf16_t* P_U1T = (bf16_t*)(wsf + 14680064);
    bf16_t* P_KT  = (bf16_t*)(wsf + 16777216);
    bf16_t* P_D   = (bf16_t*)(wsf + 19726336);
    float*  P_cs  = wsf + 20774912;
    bf16_t* WoT   = (bf16_t*)(wsf + 20807680);
    bf16_t* o16   = (bf16_t*)(wsf + 22904832);
    bf16_t* Qn    = (bf16_t*)(wsf + 25001984);

    dim3 blk(256);

    tcast<<<dim3(192, 64), blk, 0, stream>>>(W_qkv, wT, DM, CDIM);
    castk<<<dim3(4096), blk, 0, stream>>>(x, x16, (T_LEN * DM) / 4);
    mgemm<1, 6><<<dim3(768), blk, 0, stream>>>(x16, wT, nullptr, u16, T_LEN, CDIM, DM);
    ba_kernel<<<dim3(256), blk, 0, stream>>>(x, W_ba, betaT, decT);
    tcast<<<dim3(24, 192), blk, 0, stream>>>(gen_w1, wT, CDIM, GH);
    mgemm<2, 0><<<dim3(6, 16), blk, 0, stream>>>(u16, wT, nullptr, h116, T_LEN, GH, CDIM);
    tcast<<<dim3(768, 24), blk, 0, stream>>>(gen_w2, wT, GH, NOUT);
    convgen<<<dim3(3072), blk, 0, stream>>>(h116, wT, gen_b2, u16, cv);
    dr_phase1<<<dim3(512), blk, 0, stream>>>(cv, decT, betaT, P_W, P_U1T, P_KT, P_D, P_cs, Qn);
    tcast<<<dim3(64, 64), blk, 0, stream>>>(W_o, WoT, DM, DM);
    dr_phase2<<<dim3(32), blk, 0, stream>>>(Qn, P_W, P_U1T, P_KT, P_D, P_cs, o16);
    mgemm<0, 2><<<dim3(256), blk, 0, stream>>>(o16, WoT, y, nullptr, T_LEN, DM, DM);
}